// Round 6
// baseline (553.945 us; speedup 1.0000x reference)
//
#include <hip/hip_runtime.h>
#include <hip/hip_bf16.h>

#define N_NODES 30000
#define N_EDGES 1000000
#define N_GRAPHS 256
#define HEADS 8
#define DHEAD 16
#define HIDDEN 128
#define LAYERS 3
#define KPN 17
#define KPE 16
#define NEG_SLOPE 0.2f
#define BN_EPS 1e-5f
#define ET (N_EDGES + N_NODES)
#define NBUCK 938          /* ceil(30000/32) */
#define BCAP 4090          /* >> max bucket load (mean ~1100, sigma ~33) */

__device__ __forceinline__ unsigned bf16_rne(float f) {
    unsigned u = __float_as_uint(f);
    return (u + 0x7fffu + ((u >> 16) & 1u)) >> 16;
}

// ---------------- CSR build: binned counting sort ----------------
// Pass A: append packed (src | dstlo<<15) into coarse buckets of 32 dst nodes.
__global__ void k_bucket(const int* __restrict__ ei, int* __restrict__ bcnt,
                         unsigned* __restrict__ bdata) {
    int t = blockIdx.x * 256 + threadIdx.x;
    if (t >= ET) return;
    int s, d;
    if (t < N_EDGES) { s = ei[t]; d = ei[N_EDGES + t]; }
    else { s = t - N_EDGES; d = s; }
    int b = d >> 5;
    int pos = atomicAdd(&bcnt[b], 1);
    bdata[(size_t)b * BCAP + pos] = (unsigned)s | ((unsigned)(d & 31) << 15);
}

// Pass B1: per-node degree from buckets (LDS histogram)
__global__ __launch_bounds__(256) void k_bcnt(const int* __restrict__ bcnt,
                                              const unsigned* __restrict__ bdata,
                                              int* __restrict__ cnt) {
    __shared__ int hist[32];
    int b = blockIdx.x;
    if (threadIdx.x < 32) hist[threadIdx.x] = 0;
    __syncthreads();
    int n = bcnt[b];
    for (int t = threadIdx.x; t < n; t += 256) {
        unsigned e = bdata[(size_t)b * BCAP + t];
        atomicAdd(&hist[(e >> 15) & 31], 1);
    }
    __syncthreads();
    if (threadIdx.x < 32) {
        int node = b * 32 + threadIdx.x;
        if (node < N_NODES) cnt[node] = hist[threadIdx.x];
    }
}

// single block prefix scan; all traffic staged through LDS
__global__ __launch_bounds__(1024) void k_scan(const int* __restrict__ cnt,
                                               int* __restrict__ ptr) {
    __shared__ int lcnt[N_NODES];
    __shared__ int sums[1024];
    int t = threadIdx.x;
    for (int i = t; i < N_NODES; i += 1024) lcnt[i] = cnt[i];
    __syncthreads();
    const int CH = 30;
    int lo = t * CH;
    int hi = lo + CH; if (hi > N_NODES) hi = N_NODES;
    int s = 0;
    for (int i = lo; i < hi; ++i) s += lcnt[i];
    sums[t] = s;
    __syncthreads();
    for (int off = 1; off < 1024; off <<= 1) {
        int v = (t >= off) ? sums[t - off] : 0;
        __syncthreads();
        sums[t] += v;
        __syncthreads();
    }
    int base = (t == 0) ? 0 : sums[t - 1];
    for (int i = lo; i < hi; ++i) {
        int c = lcnt[i];
        lcnt[i] = base;
        base += c;
    }
    __syncthreads();
    for (int i = t; i < N_NODES; i += 1024) ptr[i] = lcnt[i];
    if (t == 0) ptr[N_NODES] = ET;
}

// Pass B2: place bucket entries into contiguous csr window (LDS offsets)
__global__ __launch_bounds__(256) void k_place(const int* __restrict__ bcnt,
                                               const unsigned* __restrict__ bdata,
                                               const int* __restrict__ ptr,
                                               int* __restrict__ csr_src) {
    __shared__ int offs[32];
    __shared__ int lcnt[32];
    int b = blockIdx.x;
    if (threadIdx.x < 32) {
        int node = b * 32 + threadIdx.x;
        offs[threadIdx.x] = (node < N_NODES) ? ptr[node] : 0;
        lcnt[threadIdx.x] = 0;
    }
    __syncthreads();
    int n = bcnt[b];
    for (int t = threadIdx.x; t < n; t += 256) {
        unsigned e = bdata[(size_t)b * BCAP + t];
        int dl = (e >> 15) & 31;
        int pos = offs[dl] + atomicAdd(&lcnt[dl], 1);
        csr_src[pos] = (int)(e & 0x7fffu);
    }
}

// ---------------- graph segment boundaries (batch is sorted) ----------------
__global__ void k_gptr(const int* __restrict__ batch, int* __restrict__ gptr) {
    int g = blockIdx.x * 256 + threadIdx.x;
    if (g > N_GRAPHS) return;
    if (g == N_GRAPHS) { gptr[g] = N_NODES; return; }
    int lo = 0, hi = N_NODES;
    while (lo < hi) {
        int mid = (lo + hi) >> 1;
        if (batch[mid] < g) lo = mid + 1; else hi = mid;
    }
    gptr[g] = lo;
}

// ---------------- input projection ----------------
__global__ void k_inproj(const float* __restrict__ x, const float* __restrict__ kp_emb,
                         const float* __restrict__ w_in, const float* __restrict__ b_in,
                         float* __restrict__ h) {
    int t = blockIdx.x * 256 + threadIdx.x;
    if (t >= N_NODES * HIDDEN) return;
    int c = t & 127, i = t >> 7;
    float acc = b_in[c];
    const float* xi = x + i * 3;
    acc += xi[0] * w_in[0 * 128 + c];
    acc += xi[1] * w_in[1 * 128 + c];
    acc += xi[2] * w_in[2 * 128 + c];
    const float* kp = kp_emb + (i % KPN) * KPE;
#pragma unroll
    for (int k = 0; k < KPE; ++k) acc += kp[k] * w_in[(3 + k) * 128 + c];
    h[t] = acc;
}

// ---------------- dual GEMM: xl(bf16) = h@wl, xr(f32) = h@wr ----------------
__global__ __launch_bounds__(256) void k_gemm(const float* __restrict__ h,
                                              const float* __restrict__ wl,
                                              const float* __restrict__ wr,
                                              unsigned* __restrict__ xlb,
                                              float* __restrict__ xr) {
    __shared__ float hs[64][132];
    int brow = blockIdx.x * 64;
    int tid = threadIdx.x;
#pragma unroll
    for (int j = 0; j < 8; ++j) {
        int flat = j * 256 + tid;
        int r = flat >> 5, c4 = flat & 31;
        int gr = brow + r;
        float4 v = make_float4(0.f, 0.f, 0.f, 0.f);
        if (gr < N_NODES) v = *(const float4*)(h + (size_t)gr * 128 + c4 * 4);
        *(float4*)&hs[r][c4 * 4] = v;
    }
    __syncthreads();
    int cg = tid & 31, rg = tid >> 5;
    const float* wbase = (cg < 16) ? (wl + cg * 8) : (wr + (cg - 16) * 8);
    float acc[8][8];
#pragma unroll
    for (int j = 0; j < 8; ++j)
#pragma unroll
        for (int q = 0; q < 8; ++q) acc[j][q] = 0.f;

    for (int k = 0; k < 128; ++k) {
        float4 w0 = *(const float4*)(wbase + k * 128);
        float4 w1 = *(const float4*)(wbase + k * 128 + 4);
        float hv[8];
#pragma unroll
        for (int j = 0; j < 8; ++j) hv[j] = hs[rg * 8 + j][k];
#pragma unroll
        for (int j = 0; j < 8; ++j) {
            acc[j][0] += hv[j] * w0.x; acc[j][1] += hv[j] * w0.y;
            acc[j][2] += hv[j] * w0.z; acc[j][3] += hv[j] * w0.w;
            acc[j][4] += hv[j] * w1.x; acc[j][5] += hv[j] * w1.y;
            acc[j][6] += hv[j] * w1.z; acc[j][7] += hv[j] * w1.w;
        }
    }
#pragma unroll
    for (int j = 0; j < 8; ++j) {
        int gr = brow + rg * 8 + j;
        if (gr >= N_NODES) continue;
        if (cg < 16) {
            uint4 o;
            o.x = bf16_rne(acc[j][0]) | (bf16_rne(acc[j][1]) << 16);
            o.y = bf16_rne(acc[j][2]) | (bf16_rne(acc[j][3]) << 16);
            o.z = bf16_rne(acc[j][4]) | (bf16_rne(acc[j][5]) << 16);
            o.w = bf16_rne(acc[j][6]) | (bf16_rne(acc[j][7]) << 16);
            *(uint4*)(xlb + (size_t)gr * 64 + cg * 4) = o;
        } else {
            float* dst = xr + (size_t)gr * 128 + (cg - 16) * 8;
            *(float4*)(dst)     = make_float4(acc[j][0], acc[j][1], acc[j][2], acc[j][3]);
            *(float4*)(dst + 4) = make_float4(acc[j][4], acc[j][5], acc[j][6], acc[j][7]);
        }
    }
}

// ---------------- GATv2 per-node kernel ----------------
// 1 wave per node; 2 edges per iteration (32 lanes each, 4 dims/lane);
// no-max softmax; depth-2 pair pipeline (4 edges in flight)
__global__ __launch_bounds__(256) void k_gat(const unsigned* __restrict__ xlb,
                                             const float* __restrict__ xr,
                                             const int* __restrict__ ptr,
                                             const int* __restrict__ csr_src,
                                             const float* __restrict__ att_l,
                                             const float* __restrict__ bias_l,
                                             const float* __restrict__ gamma_l,
                                             const float* __restrict__ beta_l,
                                             const float* __restrict__ mean_l,
                                             const float* __restrict__ var_l,
                                             float* __restrict__ h) {
    int wid = (blockIdx.x * 256 + threadIdx.x) >> 6;
    int lane = threadIdx.x & 63;
    if (wid >= N_NODES) return;
    int i = wid;
    int grp = lane >> 5;
    int l32 = lane & 31;
    int d0 = 4 * l32;

    float4 xrv = *(const float4*)(xr + (size_t)i * 128 + d0);
    const float L2E = 1.44269504089f;
    float4 av = *(const float4*)(att_l + d0);
    av.x *= L2E; av.y *= L2E; av.z *= L2E; av.w *= L2E;
    int e0 = ptr[i], e1 = ptr[i + 1];

    float denom = 0.f, acc0 = 0.f, acc1 = 0.f, acc2 = 0.f, acc3 = 0.f;

#define LDP(KP, WREG, VREG) { \
    int eo = 2 * (KP) + grp; \
    int sr = __shfl(sv, eo); \
    VREG = eo < cnt; \
    int rw = VREG ? sr : 0; \
    WREG = *(const uint2*)(xlb + ((size_t)rw << 6) + (l32 << 1)); \
}
#define PROCP(WREG, VREG) { \
    float v0 = __uint_as_float(WREG.x << 16); \
    float v1 = __uint_as_float(WREG.x & 0xffff0000u); \
    float v2 = __uint_as_float(WREG.y << 16); \
    float v3 = __uint_as_float(WREG.y & 0xffff0000u); \
    float z0 = v0 + xrv.x, z1 = v1 + xrv.y, z2 = v2 + xrv.z, z3 = v3 + xrv.w; \
    z0 = fmaxf(z0, NEG_SLOPE * z0); \
    z1 = fmaxf(z1, NEG_SLOPE * z1); \
    z2 = fmaxf(z2, NEG_SLOPE * z2); \
    z3 = fmaxf(z3, NEG_SLOPE * z3); \
    float p = z0 * av.x + z1 * av.y + z2 * av.z + z3 * av.w; \
    p += __shfl_xor(p, 1); \
    p += __shfl_xor(p, 2); \
    float ex = VREG ? exp2f(p) : 0.f; \
    denom += ex; \
    acc0 += ex * v0; acc1 += ex * v1; acc2 += ex * v2; acc3 += ex * v3; \
}

    for (int base = e0; base < e1; base += 64) {
        int idx = base + lane;
        int sv = (idx < e1) ? csr_src[idx] : 0;
        int cnt = e1 - base; if (cnt > 64) cnt = 64;
        int np = (cnt + 1) >> 1;

        uint2 w0, w1; bool b0 = false, b1 = false;
        LDP(0, w0, b0);
        if (1 < np) LDP(1, w1, b1);
        int k = 0;
        for (; k + 2 < np; k += 2) {
            uint2 n0, n1; bool c0, c1;
            LDP(k + 2, n0, c0);
            LDP(k + 3, n1, c1);
            PROCP(w0, b0); PROCP(w1, b1);
            w0 = n0; b0 = c0; w1 = n1; b1 = c1;
        }
        PROCP(w0, b0);
        if (k + 1 < np) PROCP(w1, b1);
    }
#undef LDP
#undef PROCP

    // combine the two 32-lane halves
    denom += __shfl_xor(denom, 32);
    acc0 += __shfl_xor(acc0, 32);
    acc1 += __shfl_xor(acc1, 32);
    acc2 += __shfl_xor(acc2, 32);
    acc3 += __shfl_xor(acc3, 32);

    if (grp == 0) {
        float inv = 1.f / denom;
        float4 bia = *(const float4*)(bias_l + d0);
        float4 gam = *(const float4*)(gamma_l + d0);
        float4 bet = *(const float4*)(beta_l + d0);
        float4 mea = *(const float4*)(mean_l + d0);
        float4 var = *(const float4*)(var_l + d0);
        float o0 = fmaxf(acc0 * inv + bia.x, 0.f);
        float o1 = fmaxf(acc1 * inv + bia.y, 0.f);
        float o2 = fmaxf(acc2 * inv + bia.z, 0.f);
        float o3 = fmaxf(acc3 * inv + bia.w, 0.f);
        o0 = (o0 - mea.x) * (gam.x * rsqrtf(var.x + BN_EPS)) + bet.x;
        o1 = (o1 - mea.y) * (gam.y * rsqrtf(var.y + BN_EPS)) + bet.y;
        o2 = (o2 - mea.z) * (gam.z * rsqrtf(var.z + BN_EPS)) + bet.z;
        o3 = (o3 - mea.w) * (gam.w * rsqrtf(var.w + BN_EPS)) + bet.w;
        float4 hv = *(const float4*)(h + (size_t)i * 128 + d0);
        hv.x += o0; hv.y += o1; hv.z += o2; hv.w += o3;
        *(float4*)(h + (size_t)i * 128 + d0) = hv;
    }
}

// ---------------- pooling: one block per graph, segment sum, no atomics ----------------
__global__ __launch_bounds__(256) void k_pool_seg(const float* __restrict__ h,
                                                  const int* __restrict__ gptr,
                                                  float* __restrict__ pool) {
    __shared__ float red[256];
    int b = blockIdx.x;
    int c = threadIdx.x & 127, half = threadIdx.x >> 7;
    int lo = gptr[b], hi = gptr[b + 1];
    float s = 0.f;
    for (int i = lo + half; i < hi; i += 2) s += h[(size_t)i * 128 + c];
    red[threadIdx.x] = s;
    __syncthreads();
    if (half == 0) pool[b * 128 + c] = red[c] + red[c + 128];
}

// ---------------- classifier MLP (1 block per graph) ----------------
__global__ __launch_bounds__(256) void k_mlp(const float* __restrict__ pool,
                                             const int* __restrict__ gptr,
                                             const float* __restrict__ w1, const float* __restrict__ b1,
                                             const float* __restrict__ w2, const float* __restrict__ b2,
                                             const float* __restrict__ w3, const float* __restrict__ b3,
                                             float* __restrict__ out) {
    __shared__ float g[128], t1[256], t2[128];
    int b = blockIdx.x, t = threadIdx.x;
    float cnt = fmaxf((float)(gptr[b + 1] - gptr[b]), 1.0f);
    if (t < 128) g[t] = pool[b * 128 + t] / cnt;
    __syncthreads();
    {
        float acc = b1[t];
        for (int k = 0; k < 128; ++k) acc += g[k] * w1[k * 256 + t];
        t1[t] = acc > 0.f ? acc : expm1f(acc);
    }
    __syncthreads();
    if (t < 128) {
        float acc = b2[t];
        for (int k = 0; k < 256; ++k) acc += t1[k] * w2[k * 128 + t];
        t2[t] = acc > 0.f ? acc : expm1f(acc);
    }
    __syncthreads();
    if (t < 2) {
        float acc = b3[t];
        for (int k = 0; k < 128; ++k) acc += t2[k] * w3[k * 2 + t];
        out[b * 2 + t] = acc;
    }
}

// ---------------- launch ----------------
extern "C" void kernel_launch(void* const* d_in, const int* in_sizes, int n_in,
                              void* d_out, int out_size, void* d_ws, size_t ws_size,
                              hipStream_t stream) {
    const float* x        = (const float*)d_in[0];
    const int*   ei       = (const int*)d_in[1];
    const int*   batch    = (const int*)d_in[2];
    const float* kp_emb   = (const float*)d_in[3];
    const float* w_in     = (const float*)d_in[4];
    const float* b_in     = (const float*)d_in[5];
    const float* w_l      = (const float*)d_in[6];
    const float* w_r      = (const float*)d_in[7];
    const float* att      = (const float*)d_in[8];
    const float* conv_b   = (const float*)d_in[9];
    const float* bn_gamma = (const float*)d_in[10];
    const float* bn_beta  = (const float*)d_in[11];
    const float* bn_mean  = (const float*)d_in[12];
    const float* bn_var   = (const float*)d_in[13];
    const float* w1 = (const float*)d_in[14];
    const float* b1 = (const float*)d_in[15];
    const float* w2 = (const float*)d_in[16];
    const float* b2 = (const float*)d_in[17];
    const float* w3 = (const float*)d_in[18];
    const float* b3 = (const float*)d_in[19];
    float* out = (float*)d_out;

    char* ws = (char*)d_ws;
    const size_t OFF_H    = 0;
    const size_t OFF_XL   = OFF_H + (size_t)N_NODES * 128 * 4;
    const size_t OFF_XR   = OFF_XL + (size_t)N_NODES * 64 * 4;    // bdata aliases XR pre-GEMM
    const size_t OFF_PTR  = OFF_XR + (size_t)N_NODES * 128 * 4;
    const size_t OFF_CUR  = OFF_PTR + 120320;                      // bcnt lives here
    const size_t OFF_CNT  = OFF_CUR + 120320;
    const size_t OFF_SRC  = OFF_CNT + 120320;
    const size_t OFF_POOL = OFF_SRC + 4120064;
    const size_t OFF_GPTR = OFF_POOL + (size_t)N_GRAPHS * 128 * 4;

    float*    h      = (float*)(ws + OFF_H);
    unsigned* xlb    = (unsigned*)(ws + OFF_XL);
    float*    xr     = (float*)(ws + OFF_XR);
    unsigned* bdata  = (unsigned*)(ws + OFF_XR);   // alias: free until k_gemm
    int*      ptr    = (int*)(ws + OFF_PTR);
    int*      bcnt   = (int*)(ws + OFF_CUR);
    int*      cnt    = (int*)(ws + OFF_CNT);
    int*      csrsrc = (int*)(ws + OFF_SRC);
    float*    pool   = (float*)(ws + OFF_POOL);
    int*      gptr   = (int*)(ws + OFF_GPTR);

    hipMemsetAsync(bcnt, 0, NBUCK * 4, stream);
    k_bucket<<<(ET + 255) / 256, 256, 0, stream>>>(ei, bcnt, bdata);
    k_bcnt<<<NBUCK, 256, 0, stream>>>(bcnt, bdata, cnt);
    k_scan<<<1, 1024, 0, stream>>>(cnt, ptr);
    k_place<<<NBUCK, 256, 0, stream>>>(bcnt, bdata, ptr, csrsrc);
    k_gptr<<<2, 256, 0, stream>>>(batch, gptr);

    k_inproj<<<(N_NODES * 128 + 255) / 256, 256, 0, stream>>>(x, kp_emb, w_in, b_in, h);

    for (int l = 0; l < LAYERS; ++l) {
        const float* wl = w_l + (size_t)l * 128 * 128;
        const float* wr = w_r + (size_t)l * 128 * 128;
        k_gemm<<<(N_NODES + 63) / 64, 256, 0, stream>>>(h, wl, wr, xlb, xr);
        k_gat<<<(N_NODES + 3) / 4, 256, 0, stream>>>(
            xlb, xr, ptr, csrsrc,
            att + (size_t)l * 128, conv_b + (size_t)l * 128,
            bn_gamma + (size_t)l * 128, bn_beta + (size_t)l * 128,
            bn_mean + (size_t)l * 128, bn_var + (size_t)l * 128, h);
    }

    k_pool_seg<<<N_GRAPHS, 256, 0, stream>>>(h, gptr, pool);
    k_mlp<<<N_GRAPHS, 256, 0, stream>>>(pool, gptr, w1, b1, w2, b2, w3, b3, out);
}

// Round 7
// 340.181 us; speedup vs baseline: 1.6284x; 1.6284x over previous
//
#include <hip/hip_runtime.h>
#include <hip/hip_bf16.h>

#define N_NODES 30000
#define N_EDGES 1000000
#define N_GRAPHS 256
#define HEADS 8
#define DHEAD 16
#define HIDDEN 128
#define LAYERS 3
#define KPN 17
#define KPE 16
#define NEG_SLOPE 0.2f
#define BN_EPS 1e-5f
#define ET (N_EDGES + N_NODES)
#define NBIN 235           /* ceil(30000/128) */
#define BINW 128           /* nodes per bin */
#define BINCAP 6144        /* mean load ~4266, +29 sigma */
#define CHUNK 4096

__device__ __forceinline__ unsigned bf16_rne(float f) {
    unsigned u = __float_as_uint(f);
    return (u + 0x7fffu + ((u >> 16) & 1u)) >> 16;
}

// ---------------- CSR build: LDS-aggregated binned counting sort ----------------
// Pass A: per-block LDS histogram over 235 bins -> bulk reservation -> grouped writes
__global__ __launch_bounds__(256) void k_bin(const int* __restrict__ ei,
                                             int* __restrict__ bcnt,
                                             unsigned* __restrict__ bdata) {
    __shared__ int lcnt[NBIN];
    __shared__ int lbase[NBIN];
    int base = blockIdx.x * CHUNK;
    int n = N_EDGES - base; if (n > CHUNK) n = CHUNK;
    for (int i = threadIdx.x; i < NBIN; i += 256) lcnt[i] = 0;
    __syncthreads();
    for (int t = threadIdx.x; t < n; t += 256) {
        int d = ei[N_EDGES + base + t];
        atomicAdd(&lcnt[d >> 7], 1);
    }
    __syncthreads();
    for (int i = threadIdx.x; i < NBIN; i += 256) {
        int c = lcnt[i];
        lbase[i] = c ? atomicAdd(&bcnt[i], c) : 0;
        lcnt[i] = 0;
    }
    __syncthreads();
    for (int t = threadIdx.x; t < n; t += 256) {
        int s = ei[base + t];
        int d = ei[N_EDGES + base + t];
        int b = d >> 7;
        int pos = lbase[b] + atomicAdd(&lcnt[b], 1);
        bdata[(size_t)b * BINCAP + pos] = (unsigned)s | ((unsigned)(d & 127) << 15);
    }
}

// scan over bin totals (edges + self-loop nodes) -> bin base offsets
__global__ __launch_bounds__(256) void k_bscan(const int* __restrict__ bcnt,
                                               int* __restrict__ bbase,
                                               int* __restrict__ ptr) {
    __shared__ int v[256];
    int t = threadIdx.x;
    int c = 0;
    if (t < NBIN) {
        int nodes = N_NODES - t * BINW; if (nodes > BINW) nodes = BINW;
        c = bcnt[t] + nodes;
    }
    v[t] = c;
    __syncthreads();
    for (int off = 1; off < 256; off <<= 1) {
        int x = (t >= off) ? v[t - off] : 0;
        __syncthreads();
        v[t] += x;
        __syncthreads();
    }
    if (t < NBIN) bbase[t] = v[t] - c;   // exclusive
    if (t == 0) ptr[N_NODES] = ET;
}

// Pass B: per-bin node histogram + prefix -> ptr + contiguous placement (L2-local window)
__global__ __launch_bounds__(256) void k_place2(const int* __restrict__ bcnt,
                                                const unsigned* __restrict__ bdata,
                                                const int* __restrict__ bbase,
                                                int* __restrict__ ptr,
                                                int* __restrict__ csr_src) {
    __shared__ int hist[BINW];
    __shared__ int pre[BINW];
    __shared__ int nodestart[BINW];
    __shared__ int lofs[BINW];
    int b = blockIdx.x;
    int tid = threadIdx.x;
    int nNodes = N_NODES - b * BINW; if (nNodes > BINW) nNodes = BINW;
    int n = bcnt[b];
    if (tid < BINW) hist[tid] = (tid < nNodes) ? 1 : 0;   // self loop seed
    __syncthreads();
    for (int t = tid; t < n; t += 256)
        atomicAdd(&hist[(bdata[(size_t)b * BINCAP + t] >> 15) & 127], 1);
    __syncthreads();
    if (tid < BINW) pre[tid] = hist[tid];
    __syncthreads();
    for (int off = 1; off < BINW; off <<= 1) {
        int x = (tid >= off && tid < BINW) ? pre[tid - off] : 0;
        __syncthreads();
        if (tid < BINW) pre[tid] += x;
        __syncthreads();
    }
    if (tid < BINW) {
        int ns = bbase[b] + pre[tid] - hist[tid];   // exclusive prefix
        nodestart[tid] = ns;
        if (tid < nNodes) {
            int node = b * BINW + tid;
            ptr[node] = ns;
            csr_src[ns] = node;     // self loop at slot 0
        }
        lofs[tid] = 1;
    }
    __syncthreads();
    for (int t = tid; t < n; t += 256) {
        unsigned e = bdata[(size_t)b * BINCAP + t];
        int dl = (e >> 15) & 127;
        int pos = nodestart[dl] + atomicAdd(&lofs[dl], 1);
        csr_src[pos] = (int)(e & 0x7fffu);
    }
}

// ---------------- graph segment boundaries (batch is sorted) ----------------
__global__ void k_gptr(const int* __restrict__ batch, int* __restrict__ gptr) {
    int g = blockIdx.x * 256 + threadIdx.x;
    if (g > N_GRAPHS) return;
    if (g == N_GRAPHS) { gptr[g] = N_NODES; return; }
    int lo = 0, hi = N_NODES;
    while (lo < hi) {
        int mid = (lo + hi) >> 1;
        if (batch[mid] < g) lo = mid + 1; else hi = mid;
    }
    gptr[g] = lo;
}

// ---------------- input projection ----------------
__global__ void k_inproj(const float* __restrict__ x, const float* __restrict__ kp_emb,
                         const float* __restrict__ w_in, const float* __restrict__ b_in,
                         float* __restrict__ h) {
    int t = blockIdx.x * 256 + threadIdx.x;
    if (t >= N_NODES * HIDDEN) return;
    int c = t & 127, i = t >> 7;
    float acc = b_in[c];
    const float* xi = x + i * 3;
    acc += xi[0] * w_in[0 * 128 + c];
    acc += xi[1] * w_in[1 * 128 + c];
    acc += xi[2] * w_in[2 * 128 + c];
    const float* kp = kp_emb + (i % KPN) * KPE;
#pragma unroll
    for (int k = 0; k < KPE; ++k) acc += kp[k] * w_in[(3 + k) * 128 + c];
    h[t] = acc;
}

// ---------------- dual GEMM: xl(bf16) = h@wl, xr(f32) = h@wr ----------------
__global__ __launch_bounds__(256) void k_gemm(const float* __restrict__ h,
                                              const float* __restrict__ wl,
                                              const float* __restrict__ wr,
                                              unsigned* __restrict__ xlb,
                                              float* __restrict__ xr) {
    __shared__ float hs[64][132];
    int brow = blockIdx.x * 64;
    int tid = threadIdx.x;
#pragma unroll
    for (int j = 0; j < 8; ++j) {
        int flat = j * 256 + tid;
        int r = flat >> 5, c4 = flat & 31;
        int gr = brow + r;
        float4 v = make_float4(0.f, 0.f, 0.f, 0.f);
        if (gr < N_NODES) v = *(const float4*)(h + (size_t)gr * 128 + c4 * 4);
        *(float4*)&hs[r][c4 * 4] = v;
    }
    __syncthreads();
    int cg = tid & 31, rg = tid >> 5;
    const float* wbase = (cg < 16) ? (wl + cg * 8) : (wr + (cg - 16) * 8);
    float acc[8][8];
#pragma unroll
    for (int j = 0; j < 8; ++j)
#pragma unroll
        for (int q = 0; q < 8; ++q) acc[j][q] = 0.f;

    for (int k = 0; k < 128; ++k) {
        float4 w0 = *(const float4*)(wbase + k * 128);
        float4 w1 = *(const float4*)(wbase + k * 128 + 4);
        float hv[8];
#pragma unroll
        for (int j = 0; j < 8; ++j) hv[j] = hs[rg * 8 + j][k];
#pragma unroll
        for (int j = 0; j < 8; ++j) {
            acc[j][0] += hv[j] * w0.x; acc[j][1] += hv[j] * w0.y;
            acc[j][2] += hv[j] * w0.z; acc[j][3] += hv[j] * w0.w;
            acc[j][4] += hv[j] * w1.x; acc[j][5] += hv[j] * w1.y;
            acc[j][6] += hv[j] * w1.z; acc[j][7] += hv[j] * w1.w;
        }
    }
#pragma unroll
    for (int j = 0; j < 8; ++j) {
        int gr = brow + rg * 8 + j;
        if (gr >= N_NODES) continue;
        if (cg < 16) {
            uint4 o;
            o.x = bf16_rne(acc[j][0]) | (bf16_rne(acc[j][1]) << 16);
            o.y = bf16_rne(acc[j][2]) | (bf16_rne(acc[j][3]) << 16);
            o.z = bf16_rne(acc[j][4]) | (bf16_rne(acc[j][5]) << 16);
            o.w = bf16_rne(acc[j][6]) | (bf16_rne(acc[j][7]) << 16);
            *(uint4*)(xlb + (size_t)gr * 64 + cg * 4) = o;
        } else {
            float* dst = xr + (size_t)gr * 128 + (cg - 16) * 8;
            *(float4*)(dst)     = make_float4(acc[j][0], acc[j][1], acc[j][2], acc[j][3]);
            *(float4*)(dst + 4) = make_float4(acc[j][4], acc[j][5], acc[j][6], acc[j][7]);
        }
    }
}

// ---------------- GATv2 per-node kernel ----------------
// 1 wave per node; 2 edges per iteration (32 lanes each, 4 dims/lane);
// no-max softmax; depth-2 pair pipeline (4 edges in flight)
__global__ __launch_bounds__(256) void k_gat(const unsigned* __restrict__ xlb,
                                             const float* __restrict__ xr,
                                             const int* __restrict__ ptr,
                                             const int* __restrict__ csr_src,
                                             const float* __restrict__ att_l,
                                             const float* __restrict__ bias_l,
                                             const float* __restrict__ gamma_l,
                                             const float* __restrict__ beta_l,
                                             const float* __restrict__ mean_l,
                                             const float* __restrict__ var_l,
                                             float* __restrict__ h) {
    int wid = (blockIdx.x * 256 + threadIdx.x) >> 6;
    int lane = threadIdx.x & 63;
    if (wid >= N_NODES) return;
    int i = wid;
    int grp = lane >> 5;
    int l32 = lane & 31;
    int d0 = 4 * l32;

    float4 xrv = *(const float4*)(xr + (size_t)i * 128 + d0);
    const float L2E = 1.44269504089f;
    float4 av = *(const float4*)(att_l + d0);
    av.x *= L2E; av.y *= L2E; av.z *= L2E; av.w *= L2E;
    int e0 = ptr[i], e1 = ptr[i + 1];

    float denom = 0.f, acc0 = 0.f, acc1 = 0.f, acc2 = 0.f, acc3 = 0.f;

#define LDP(KP, WREG, VREG) { \
    int eo = 2 * (KP) + grp; \
    int sr = __shfl(sv, eo); \
    VREG = eo < cnt; \
    int rw = VREG ? sr : 0; \
    WREG = *(const uint2*)(xlb + ((size_t)rw << 6) + (l32 << 1)); \
}
#define PROCP(WREG, VREG) { \
    float v0 = __uint_as_float(WREG.x << 16); \
    float v1 = __uint_as_float(WREG.x & 0xffff0000u); \
    float v2 = __uint_as_float(WREG.y << 16); \
    float v3 = __uint_as_float(WREG.y & 0xffff0000u); \
    float z0 = v0 + xrv.x, z1 = v1 + xrv.y, z2 = v2 + xrv.z, z3 = v3 + xrv.w; \
    z0 = fmaxf(z0, NEG_SLOPE * z0); \
    z1 = fmaxf(z1, NEG_SLOPE * z1); \
    z2 = fmaxf(z2, NEG_SLOPE * z2); \
    z3 = fmaxf(z3, NEG_SLOPE * z3); \
    float p = z0 * av.x + z1 * av.y + z2 * av.z + z3 * av.w; \
    p += __shfl_xor(p, 1); \
    p += __shfl_xor(p, 2); \
    float ex = VREG ? exp2f(p) : 0.f; \
    denom += ex; \
    acc0 += ex * v0; acc1 += ex * v1; acc2 += ex * v2; acc3 += ex * v3; \
}

    for (int base = e0; base < e1; base += 64) {
        int idx = base + lane;
        int sv = (idx < e1) ? csr_src[idx] : 0;
        int cnt = e1 - base; if (cnt > 64) cnt = 64;
        int np = (cnt + 1) >> 1;

        uint2 w0, w1; bool b0 = false, b1 = false;
        LDP(0, w0, b0);
        if (1 < np) LDP(1, w1, b1);
        int k = 0;
        for (; k + 2 < np; k += 2) {
            uint2 n0, n1; bool c0, c1;
            LDP(k + 2, n0, c0);
            LDP(k + 3, n1, c1);
            PROCP(w0, b0); PROCP(w1, b1);
            w0 = n0; b0 = c0; w1 = n1; b1 = c1;
        }
        PROCP(w0, b0);
        if (k + 1 < np) PROCP(w1, b1);
    }
#undef LDP
#undef PROCP

    denom += __shfl_xor(denom, 32);
    acc0 += __shfl_xor(acc0, 32);
    acc1 += __shfl_xor(acc1, 32);
    acc2 += __shfl_xor(acc2, 32);
    acc3 += __shfl_xor(acc3, 32);

    if (grp == 0) {
        float inv = 1.f / denom;
        float4 bia = *(const float4*)(bias_l + d0);
        float4 gam = *(const float4*)(gamma_l + d0);
        float4 bet = *(const float4*)(beta_l + d0);
        float4 mea = *(const float4*)(mean_l + d0);
        float4 var = *(const float4*)(var_l + d0);
        float o0 = fmaxf(acc0 * inv + bia.x, 0.f);
        float o1 = fmaxf(acc1 * inv + bia.y, 0.f);
        float o2 = fmaxf(acc2 * inv + bia.z, 0.f);
        float o3 = fmaxf(acc3 * inv + bia.w, 0.f);
        o0 = (o0 - mea.x) * (gam.x * rsqrtf(var.x + BN_EPS)) + bet.x;
        o1 = (o1 - mea.y) * (gam.y * rsqrtf(var.y + BN_EPS)) + bet.y;
        o2 = (o2 - mea.z) * (gam.z * rsqrtf(var.z + BN_EPS)) + bet.z;
        o3 = (o3 - mea.w) * (gam.w * rsqrtf(var.w + BN_EPS)) + bet.w;
        float4 hv = *(const float4*)(h + (size_t)i * 128 + d0);
        hv.x += o0; hv.y += o1; hv.z += o2; hv.w += o3;
        *(float4*)(h + (size_t)i * 128 + d0) = hv;
    }
}

// ---------------- pooling: one block per graph, segment sum, no atomics ----------------
__global__ __launch_bounds__(256) void k_pool_seg(const float* __restrict__ h,
                                                  const int* __restrict__ gptr,
                                                  float* __restrict__ pool) {
    __shared__ float red[256];
    int b = blockIdx.x;
    int c = threadIdx.x & 127, half = threadIdx.x >> 7;
    int lo = gptr[b], hi = gptr[b + 1];
    float s = 0.f;
    for (int i = lo + half; i < hi; i += 2) s += h[(size_t)i * 128 + c];
    red[threadIdx.x] = s;
    __syncthreads();
    if (half == 0) pool[b * 128 + c] = red[c] + red[c + 128];
}

// ---------------- classifier MLP (1 block per graph) ----------------
__global__ __launch_bounds__(256) void k_mlp(const float* __restrict__ pool,
                                             const int* __restrict__ gptr,
                                             const float* __restrict__ w1, const float* __restrict__ b1,
                                             const float* __restrict__ w2, const float* __restrict__ b2,
                                             const float* __restrict__ w3, const float* __restrict__ b3,
                                             float* __restrict__ out) {
    __shared__ float g[128], t1[256], t2[128];
    int b = blockIdx.x, t = threadIdx.x;
    float cnt = fmaxf((float)(gptr[b + 1] - gptr[b]), 1.0f);
    if (t < 128) g[t] = pool[b * 128 + t] / cnt;
    __syncthreads();
    {
        float acc = b1[t];
        for (int k = 0; k < 128; ++k) acc += g[k] * w1[k * 256 + t];
        t1[t] = acc > 0.f ? acc : expm1f(acc);
    }
    __syncthreads();
    if (t < 128) {
        float acc = b2[t];
        for (int k = 0; k < 256; ++k) acc += t1[k] * w2[k * 128 + t];
        t2[t] = acc > 0.f ? acc : expm1f(acc);
    }
    __syncthreads();
    if (t < 2) {
        float acc = b3[t];
        for (int k = 0; k < 128; ++k) acc += t2[k] * w3[k * 2 + t];
        out[b * 2 + t] = acc;
    }
}

// ---------------- launch ----------------
extern "C" void kernel_launch(void* const* d_in, const int* in_sizes, int n_in,
                              void* d_out, int out_size, void* d_ws, size_t ws_size,
                              hipStream_t stream) {
    const float* x        = (const float*)d_in[0];
    const int*   ei       = (const int*)d_in[1];
    const int*   batch    = (const int*)d_in[2];
    const float* kp_emb   = (const float*)d_in[3];
    const float* w_in     = (const float*)d_in[4];
    const float* b_in     = (const float*)d_in[5];
    const float* w_l      = (const float*)d_in[6];
    const float* w_r      = (const float*)d_in[7];
    const float* att      = (const float*)d_in[8];
    const float* conv_b   = (const float*)d_in[9];
    const float* bn_gamma = (const float*)d_in[10];
    const float* bn_beta  = (const float*)d_in[11];
    const float* bn_mean  = (const float*)d_in[12];
    const float* bn_var   = (const float*)d_in[13];
    const float* w1 = (const float*)d_in[14];
    const float* b1 = (const float*)d_in[15];
    const float* w2 = (const float*)d_in[16];
    const float* b2 = (const float*)d_in[17];
    const float* w3 = (const float*)d_in[18];
    const float* b3 = (const float*)d_in[19];
    float* out = (float*)d_out;

    char* ws = (char*)d_ws;
    const size_t OFF_H    = 0;
    const size_t OFF_XL   = OFF_H + (size_t)N_NODES * 128 * 4;
    const size_t OFF_XR   = OFF_XL + (size_t)N_NODES * 64 * 4;    // bdata aliases XR pre-GEMM
    const size_t OFF_PTR  = OFF_XR + (size_t)N_NODES * 128 * 4;
    const size_t OFF_BCNT = OFF_PTR + 120320;
    const size_t OFF_BBAS = OFF_BCNT + 120320;
    const size_t OFF_SRC  = OFF_BBAS + 120320;
    const size_t OFF_POOL = OFF_SRC + 4120064;
    const size_t OFF_GPTR = OFF_POOL + (size_t)N_GRAPHS * 128 * 4;

    float*    h      = (float*)(ws + OFF_H);
    unsigned* xlb    = (unsigned*)(ws + OFF_XL);
    float*    xr     = (float*)(ws + OFF_XR);
    unsigned* bdata  = (unsigned*)(ws + OFF_XR);   // alias: free until first k_gemm
    int*      ptr    = (int*)(ws + OFF_PTR);
    int*      bcnt   = (int*)(ws + OFF_BCNT);
    int*      bbase  = (int*)(ws + OFF_BBAS);
    int*      csrsrc = (int*)(ws + OFF_SRC);
    float*    pool   = (float*)(ws + OFF_POOL);
    int*      gptr   = (int*)(ws + OFF_GPTR);

    hipMemsetAsync(bcnt, 0, NBIN * 4, stream);
    k_bin<<<(N_EDGES + CHUNK - 1) / CHUNK, 256, 0, stream>>>(ei, bcnt, bdata);
    k_bscan<<<1, 256, 0, stream>>>(bcnt, bbase, ptr);
    k_place2<<<NBIN, 256, 0, stream>>>(bcnt, bdata, bbase, ptr, csrsrc);
    k_gptr<<<2, 256, 0, stream>>>(batch, gptr);

    k_inproj<<<(N_NODES * 128 + 255) / 256, 256, 0, stream>>>(x, kp_emb, w_in, b_in, h);

    for (int l = 0; l < LAYERS; ++l) {
        const float* wl = w_l + (size_t)l * 128 * 128;
        const float* wr = w_r + (size_t)l * 128 * 128;
        k_gemm<<<(N_NODES + 63) / 64, 256, 0, stream>>>(h, wl, wr, xlb, xr);
        k_gat<<<(N_NODES + 3) / 4, 256, 0, stream>>>(
            xlb, xr, ptr, csrsrc,
            att + (size_t)l * 128, conv_b + (size_t)l * 128,
            bn_gamma + (size_t)l * 128, bn_beta + (size_t)l * 128,
            bn_mean + (size_t)l * 128, bn_var + (size_t)l * 128, h);
    }

    k_pool_seg<<<N_GRAPHS, 256, 0, stream>>>(h, gptr, pool);
    k_mlp<<<N_GRAPHS, 256, 0, stream>>>(pool, gptr, w1, b1, w2, b2, w3, b3, out);
}

// Round 8
// 284.797 us; speedup vs baseline: 1.9450x; 1.1945x over previous
//
#include <hip/hip_runtime.h>
#include <hip/hip_bf16.h>

#define N_NODES 30000
#define N_EDGES 1000000
#define N_GRAPHS 256
#define HEADS 8
#define DHEAD 16
#define HIDDEN 128
#define LAYERS 3
#define KPN 17
#define KPE 16
#define NEG_SLOPE 0.2f
#define BN_EPS 1e-5f
#define ET (N_EDGES + N_NODES)
#define NBIN 235           /* ceil(30000/128) */
#define BINW 128           /* nodes per bin */
#define BINCAP 6144        /* mean load ~4266 */
#define CHUNK 4096

typedef __attribute__((ext_vector_type(8))) short bf16x8;
typedef __attribute__((ext_vector_type(4))) float f32x4;

__device__ __forceinline__ unsigned bf16_rne(float f) {
    unsigned u = __float_as_uint(f);
    return (u + 0x7fffu + ((u >> 16) & 1u)) >> 16;
}

// ---------------- CSR build: LDS-aggregated binned counting sort ----------------
__global__ __launch_bounds__(256) void k_bin(const int* __restrict__ ei,
                                             int* __restrict__ bcnt,
                                             unsigned* __restrict__ bdata) {
    __shared__ int lcnt[NBIN];
    __shared__ int lbase[NBIN];
    int base = blockIdx.x * CHUNK;
    int n = N_EDGES - base; if (n > CHUNK) n = CHUNK;
    for (int i = threadIdx.x; i < NBIN; i += 256) lcnt[i] = 0;
    __syncthreads();
    for (int t = threadIdx.x; t < n; t += 256) {
        int d = ei[N_EDGES + base + t];
        atomicAdd(&lcnt[d >> 7], 1);
    }
    __syncthreads();
    for (int i = threadIdx.x; i < NBIN; i += 256) {
        int c = lcnt[i];
        lbase[i] = c ? atomicAdd(&bcnt[i], c) : 0;
        lcnt[i] = 0;
    }
    __syncthreads();
    for (int t = threadIdx.x; t < n; t += 256) {
        int s = ei[base + t];
        int d = ei[N_EDGES + base + t];
        int b = d >> 7;
        int pos = lbase[b] + atomicAdd(&lcnt[b], 1);
        bdata[(size_t)b * BINCAP + pos] = (unsigned)s | ((unsigned)(d & 127) << 15);
    }
}

__global__ __launch_bounds__(256) void k_bscan(const int* __restrict__ bcnt,
                                               int* __restrict__ bbase,
                                               int* __restrict__ ptr) {
    __shared__ int v[256];
    int t = threadIdx.x;
    int c = 0;
    if (t < NBIN) {
        int nodes = N_NODES - t * BINW; if (nodes > BINW) nodes = BINW;
        c = bcnt[t] + nodes;
    }
    v[t] = c;
    __syncthreads();
    for (int off = 1; off < 256; off <<= 1) {
        int x = (t >= off) ? v[t - off] : 0;
        __syncthreads();
        v[t] += x;
        __syncthreads();
    }
    if (t < NBIN) bbase[t] = v[t] - c;
    if (t == 0) ptr[N_NODES] = ET;
}

__global__ __launch_bounds__(256) void k_place2(const int* __restrict__ bcnt,
                                                const unsigned* __restrict__ bdata,
                                                const int* __restrict__ bbase,
                                                int* __restrict__ ptr,
                                                unsigned short* __restrict__ csr_src) {
    __shared__ int hist[BINW];
    __shared__ int pre[BINW];
    __shared__ int nodestart[BINW];
    __shared__ int lofs[BINW];
    int b = blockIdx.x;
    int tid = threadIdx.x;
    int nNodes = N_NODES - b * BINW; if (nNodes > BINW) nNodes = BINW;
    int n = bcnt[b];
    if (tid < BINW) hist[tid] = (tid < nNodes) ? 1 : 0;   // self loop seed
    __syncthreads();
    for (int t = tid; t < n; t += 256)
        atomicAdd(&hist[(bdata[(size_t)b * BINCAP + t] >> 15) & 127], 1);
    __syncthreads();
    if (tid < BINW) pre[tid] = hist[tid];
    __syncthreads();
    for (int off = 1; off < BINW; off <<= 1) {
        int x = (tid >= off && tid < BINW) ? pre[tid - off] : 0;
        __syncthreads();
        if (tid < BINW) pre[tid] += x;
        __syncthreads();
    }
    if (tid < BINW) {
        int ns = bbase[b] + pre[tid] - hist[tid];
        nodestart[tid] = ns;
        if (tid < nNodes) {
            int node = b * BINW + tid;
            ptr[node] = ns;
            csr_src[ns] = (unsigned short)node;   // self loop
        }
        lofs[tid] = 1;
    }
    __syncthreads();
    for (int t = tid; t < n; t += 256) {
        unsigned e = bdata[(size_t)b * BINCAP + t];
        int dl = (e >> 15) & 127;
        int pos = nodestart[dl] + atomicAdd(&lofs[dl], 1);
        csr_src[pos] = (unsigned short)(e & 0x7fffu);
    }
}

// ---------------- graph segment boundaries ----------------
__global__ void k_gptr(const int* __restrict__ batch, int* __restrict__ gptr) {
    int g = blockIdx.x * 256 + threadIdx.x;
    if (g > N_GRAPHS) return;
    if (g == N_GRAPHS) { gptr[g] = N_NODES; return; }
    int lo = 0, hi = N_NODES;
    while (lo < hi) {
        int mid = (lo + hi) >> 1;
        if (batch[mid] < g) lo = mid + 1; else hi = mid;
    }
    gptr[g] = lo;
}

// ---------------- weight transpose+convert: wT[l][256 col][128 k] bf16 ----------------
__global__ void k_wconv(const float* __restrict__ w_l, const float* __restrict__ w_r,
                        unsigned short* __restrict__ wT) {
    int t = blockIdx.x * 256 + threadIdx.x;
    if (t >= LAYERS * 256 * 128) return;
    int l = t / (256 * 128);
    int rem = t - l * 256 * 128;
    int c = rem >> 7;
    int k = rem & 127;
    float v = (c < 128) ? w_l[(size_t)l * 16384 + k * 128 + c]
                        : w_r[(size_t)l * 16384 + k * 128 + (c - 128)];
    wT[t] = (unsigned short)bf16_rne(v);
}

// ---------------- input projection: h (f32) + hb (bf16) ----------------
__global__ void k_inproj(const float* __restrict__ x, const float* __restrict__ kp_emb,
                         const float* __restrict__ w_in, const float* __restrict__ b_in,
                         float* __restrict__ h, unsigned short* __restrict__ hb) {
    int t = blockIdx.x * 256 + threadIdx.x;
    if (t >= N_NODES * HIDDEN) return;
    int c = t & 127, i = t >> 7;
    float acc = b_in[c];
    const float* xi = x + i * 3;
    acc += xi[0] * w_in[0 * 128 + c];
    acc += xi[1] * w_in[1 * 128 + c];
    acc += xi[2] * w_in[2 * 128 + c];
    const float* kp = kp_emb + (i % KPN) * KPE;
#pragma unroll
    for (int k = 0; k < KPE; ++k) acc += kp[k] * w_in[(3 + k) * 128 + c];
    h[t] = acc;
    hb[t] = (unsigned short)bf16_rne(acc);
}

// ---------------- MFMA dual GEMM: [xl|xr](bf16) = hb(bf16) @ wT^T ----------------
// 32 rows x 256 cols per block; 4 waves x (2 M-frags x 4 N-frags); K=128 in 4 steps.
// A frag: row=lane&15, k=(lane>>4)*8+j (contiguous). B frag: col=lane&15, same k (wT is K-contiguous).
// D frag: col=lane&15, row=(lane>>4)*4+j.
__global__ __launch_bounds__(256) void k_gemm(const unsigned short* __restrict__ hb,
                                              const unsigned short* __restrict__ wT,
                                              unsigned short* __restrict__ xlb,
                                              unsigned short* __restrict__ xrb) {
    int wave = threadIdx.x >> 6;
    int lane = threadIdx.x & 63;
    int brow = blockIdx.x * 32;
    int lr = lane & 15;
    int lk = lane >> 4;
    int ar0 = brow + lr;
    int ar1 = brow + 16 + lr;
    int ar0c = ar0 < N_NODES ? ar0 : N_NODES - 1;
    int ar1c = ar1 < N_NODES ? ar1 : N_NODES - 1;
    int c0 = wave * 64 + lr;

    const unsigned short* ha0 = hb + (size_t)ar0c * 128 + lk * 8;
    const unsigned short* ha1 = hb + (size_t)ar1c * 128 + lk * 8;
    const unsigned short* wb  = wT + (size_t)c0 * 128 + lk * 8;

    f32x4 acc[2][4];
#pragma unroll
    for (int m = 0; m < 2; ++m)
#pragma unroll
        for (int n = 0; n < 4; ++n) acc[m][n] = (f32x4){0.f, 0.f, 0.f, 0.f};

#pragma unroll
    for (int ks = 0; ks < 4; ++ks) {
        bf16x8 a0 = *(const bf16x8*)(ha0 + ks * 32);
        bf16x8 a1 = *(const bf16x8*)(ha1 + ks * 32);
#pragma unroll
        for (int nt = 0; nt < 4; ++nt) {
            bf16x8 b = *(const bf16x8*)(wb + nt * 16 * 128 + ks * 32);
            acc[0][nt] = __builtin_amdgcn_mfma_f32_16x16x32_bf16(a0, b, acc[0][nt], 0, 0, 0);
            acc[1][nt] = __builtin_amdgcn_mfma_f32_16x16x32_bf16(a1, b, acc[1][nt], 0, 0, 0);
        }
    }

    int drow0 = brow + lk * 4;
#pragma unroll
    for (int mt = 0; mt < 2; ++mt) {
#pragma unroll
        for (int nt = 0; nt < 4; ++nt) {
            int col = c0 + nt * 16;
#pragma unroll
            for (int j = 0; j < 4; ++j) {
                int grow = drow0 + mt * 16 + j;
                if (grow >= N_NODES) continue;
                unsigned short bv = (unsigned short)bf16_rne(acc[mt][nt][j]);
                if (col < 128) xlb[(size_t)grow * 128 + col] = bv;
                else           xrb[(size_t)grow * 128 + (col - 128)] = bv;
            }
        }
    }
}

// ---------------- GATv2 per-node kernel ----------------
// 1 wave per node; 2 edges/iter (32 lanes each, 4 dims/lane); no-max softmax
__global__ __launch_bounds__(256) void k_gat(const unsigned* __restrict__ xlb,
                                             const unsigned* __restrict__ xrb,
                                             const int* __restrict__ ptr,
                                             const unsigned short* __restrict__ csr_src,
                                             const float* __restrict__ att_l,
                                             const float* __restrict__ bias_l,
                                             const float* __restrict__ gamma_l,
                                             const float* __restrict__ beta_l,
                                             const float* __restrict__ mean_l,
                                             const float* __restrict__ var_l,
                                             float* __restrict__ h,
                                             unsigned short* __restrict__ hb) {
    int wid = (blockIdx.x * 256 + threadIdx.x) >> 6;
    int lane = threadIdx.x & 63;
    if (wid >= N_NODES) return;
    int i = wid;
    int grp = lane >> 5;
    int l32 = lane & 31;
    int d0 = 4 * l32;

    uint2 xw = *(const uint2*)(xrb + ((size_t)i << 6) + (l32 << 1));
    float xr0 = __uint_as_float(xw.x << 16);
    float xr1 = __uint_as_float(xw.x & 0xffff0000u);
    float xr2 = __uint_as_float(xw.y << 16);
    float xr3 = __uint_as_float(xw.y & 0xffff0000u);
    const float L2E = 1.44269504089f;
    float4 av = *(const float4*)(att_l + d0);
    av.x *= L2E; av.y *= L2E; av.z *= L2E; av.w *= L2E;
    int e0 = ptr[i], e1 = ptr[i + 1];

    float denom = 0.f, acc0 = 0.f, acc1 = 0.f, acc2 = 0.f, acc3 = 0.f;

#define LDP(KP, WREG, VREG) { \
    int eo = 2 * (KP) + grp; \
    int sr = __shfl(sv, eo); \
    VREG = eo < cnt; \
    int rw = VREG ? sr : 0; \
    WREG = *(const uint2*)(xlb + ((size_t)rw << 6) + (l32 << 1)); \
}
#define PROCP(WREG, VREG) { \
    float v0 = __uint_as_float(WREG.x << 16); \
    float v1 = __uint_as_float(WREG.x & 0xffff0000u); \
    float v2 = __uint_as_float(WREG.y << 16); \
    float v3 = __uint_as_float(WREG.y & 0xffff0000u); \
    float z0 = v0 + xr0, z1 = v1 + xr1, z2 = v2 + xr2, z3 = v3 + xr3; \
    z0 = fmaxf(z0, NEG_SLOPE * z0); \
    z1 = fmaxf(z1, NEG_SLOPE * z1); \
    z2 = fmaxf(z2, NEG_SLOPE * z2); \
    z3 = fmaxf(z3, NEG_SLOPE * z3); \
    float p = z0 * av.x + z1 * av.y + z2 * av.z + z3 * av.w; \
    p += __shfl_xor(p, 1); \
    p += __shfl_xor(p, 2); \
    float ex = VREG ? exp2f(p) : 0.f; \
    denom += ex; \
    acc0 += ex * v0; acc1 += ex * v1; acc2 += ex * v2; acc3 += ex * v3; \
}

    for (int base = e0; base < e1; base += 64) {
        int idx = base + lane;
        int sv = (idx < e1) ? (int)csr_src[idx] : 0;
        int cnt = e1 - base; if (cnt > 64) cnt = 64;
        int np = (cnt + 1) >> 1;

        uint2 w0, w1; bool b0 = false, b1 = false;
        LDP(0, w0, b0);
        if (1 < np) LDP(1, w1, b1);
        int k = 0;
        for (; k + 2 < np; k += 2) {
            uint2 n0, n1; bool c0v, c1v;
            LDP(k + 2, n0, c0v);
            LDP(k + 3, n1, c1v);
            PROCP(w0, b0); PROCP(w1, b1);
            w0 = n0; b0 = c0v; w1 = n1; b1 = c1v;
        }
        PROCP(w0, b0);
        if (k + 1 < np) PROCP(w1, b1);
    }
#undef LDP
#undef PROCP

    denom += __shfl_xor(denom, 32);
    acc0 += __shfl_xor(acc0, 32);
    acc1 += __shfl_xor(acc1, 32);
    acc2 += __shfl_xor(acc2, 32);
    acc3 += __shfl_xor(acc3, 32);

    if (grp == 0) {
        float inv = 1.f / denom;
        float4 bia = *(const float4*)(bias_l + d0);
        float4 gam = *(const float4*)(gamma_l + d0);
        float4 bet = *(const float4*)(beta_l + d0);
        float4 mea = *(const float4*)(mean_l + d0);
        float4 var = *(const float4*)(var_l + d0);
        float o0 = fmaxf(acc0 * inv + bia.x, 0.f);
        float o1 = fmaxf(acc1 * inv + bia.y, 0.f);
        float o2 = fmaxf(acc2 * inv + bia.z, 0.f);
        float o3 = fmaxf(acc3 * inv + bia.w, 0.f);
        o0 = (o0 - mea.x) * (gam.x * rsqrtf(var.x + BN_EPS)) + bet.x;
        o1 = (o1 - mea.y) * (gam.y * rsqrtf(var.y + BN_EPS)) + bet.y;
        o2 = (o2 - mea.z) * (gam.z * rsqrtf(var.z + BN_EPS)) + bet.z;
        o3 = (o3 - mea.w) * (gam.w * rsqrtf(var.w + BN_EPS)) + bet.w;
        float4 hv = *(const float4*)(h + (size_t)i * 128 + d0);
        hv.x += o0; hv.y += o1; hv.z += o2; hv.w += o3;
        *(float4*)(h + (size_t)i * 128 + d0) = hv;
        unsigned pk0 = bf16_rne(hv.x) | (bf16_rne(hv.y) << 16);
        unsigned pk1 = bf16_rne(hv.z) | (bf16_rne(hv.w) << 16);
        uint2 pk; pk.x = pk0; pk.y = pk1;
        *(uint2*)(hb + (size_t)i * 128 + d0) = pk;
    }
}

// ---------------- pooling ----------------
__global__ __launch_bounds__(256) void k_pool_seg(const float* __restrict__ h,
                                                  const int* __restrict__ gptr,
                                                  float* __restrict__ pool) {
    __shared__ float red[256];
    int b = blockIdx.x;
    int c = threadIdx.x & 127, half = threadIdx.x >> 7;
    int lo = gptr[b], hi = gptr[b + 1];
    float s = 0.f;
    for (int i = lo + half; i < hi; i += 2) s += h[(size_t)i * 128 + c];
    red[threadIdx.x] = s;
    __syncthreads();
    if (half == 0) pool[b * 128 + c] = red[c] + red[c + 128];
}

// ---------------- classifier MLP ----------------
__global__ __launch_bounds__(256) void k_mlp(const float* __restrict__ pool,
                                             const int* __restrict__ gptr,
                                             const float* __restrict__ w1, const float* __restrict__ b1,
                                             const float* __restrict__ w2, const float* __restrict__ b2,
                                             const float* __restrict__ w3, const float* __restrict__ b3,
                                             float* __restrict__ out) {
    __shared__ float g[128], t1[256], t2[128];
    int b = blockIdx.x, t = threadIdx.x;
    float cnt = fmaxf((float)(gptr[b + 1] - gptr[b]), 1.0f);
    if (t < 128) g[t] = pool[b * 128 + t] / cnt;
    __syncthreads();
    {
        float acc = b1[t];
        for (int k = 0; k < 128; ++k) acc += g[k] * w1[k * 256 + t];
        t1[t] = acc > 0.f ? acc : expm1f(acc);
    }
    __syncthreads();
    if (t < 128) {
        float acc = b2[t];
        for (int k = 0; k < 256; ++k) acc += t1[k] * w2[k * 128 + t];
        t2[t] = acc > 0.f ? acc : expm1f(acc);
    }
    __syncthreads();
    if (t < 2) {
        float acc = b3[t];
        for (int k = 0; k < 128; ++k) acc += t2[k] * w3[k * 2 + t];
        out[b * 2 + t] = acc;
    }
}

// ---------------- launch ----------------
extern "C" void kernel_launch(void* const* d_in, const int* in_sizes, int n_in,
                              void* d_out, int out_size, void* d_ws, size_t ws_size,
                              hipStream_t stream) {
    const float* x        = (const float*)d_in[0];
    const int*   ei       = (const int*)d_in[1];
    const int*   batch    = (const int*)d_in[2];
    const float* kp_emb   = (const float*)d_in[3];
    const float* w_in     = (const float*)d_in[4];
    const float* b_in     = (const float*)d_in[5];
    const float* w_l      = (const float*)d_in[6];
    const float* w_r      = (const float*)d_in[7];
    const float* att      = (const float*)d_in[8];
    const float* conv_b   = (const float*)d_in[9];
    const float* bn_gamma = (const float*)d_in[10];
    const float* bn_beta  = (const float*)d_in[11];
    const float* bn_mean  = (const float*)d_in[12];
    const float* bn_var   = (const float*)d_in[13];
    const float* w1 = (const float*)d_in[14];
    const float* b1 = (const float*)d_in[15];
    const float* w2 = (const float*)d_in[16];
    const float* b2 = (const float*)d_in[17];
    const float* w3 = (const float*)d_in[18];
    const float* b3 = (const float*)d_in[19];
    float* out = (float*)d_out;

    char* ws = (char*)d_ws;
    const size_t OFF_H    = 0;                                    // f32 h [30000][128]
    const size_t OFF_HB   = OFF_H    + 15360000;                  // bf16 h
    const size_t OFF_XL   = OFF_HB   + 7680000;                   // bf16 xl
    const size_t OFF_XR   = OFF_XL   + 7680000;                   // bf16 xr (bdata alias: 5,775,360 B)
    const size_t OFF_WT   = OFF_XR   + 7680000;                   // bf16 wT [3][256][128]
    const size_t OFF_PTR  = OFF_WT   + 196608;
    const size_t OFF_BCNT = OFF_PTR  + 120320;
    const size_t OFF_BBAS = OFF_BCNT + 1024;
    const size_t OFF_SRC  = OFF_BBAS + 1024;                      // ushort csr [ET]
    const size_t OFF_POOL = OFF_SRC  + 2060032;
    const size_t OFF_GPTR = OFF_POOL + 131072;                    // end ~40.9 MB

    float*          h      = (float*)(ws + OFF_H);
    unsigned short* hb     = (unsigned short*)(ws + OFF_HB);
    unsigned short* xlb    = (unsigned short*)(ws + OFF_XL);
    unsigned short* xrb    = (unsigned short*)(ws + OFF_XR);
    unsigned*       bdata  = (unsigned*)(ws + OFF_XR);            // alias, pre-GEMM only
    unsigned short* wT     = (unsigned short*)(ws + OFF_WT);
    int*            ptr    = (int*)(ws + OFF_PTR);
    int*            bcnt   = (int*)(ws + OFF_BCNT);
    int*            bbase  = (int*)(ws + OFF_BBAS);
    unsigned short* csrsrc = (unsigned short*)(ws + OFF_SRC);
    float*          pool   = (float*)(ws + OFF_POOL);
    int*            gptr   = (int*)(ws + OFF_GPTR);

    hipMemsetAsync(bcnt, 0, NBIN * 4, stream);
    k_bin<<<(N_EDGES + CHUNK - 1) / CHUNK, 256, 0, stream>>>(ei, bcnt, bdata);
    k_bscan<<<1, 256, 0, stream>>>(bcnt, bbase, ptr);
    k_place2<<<NBIN, 256, 0, stream>>>(bcnt, bdata, bbase, ptr, csrsrc);
    k_gptr<<<2, 256, 0, stream>>>(batch, gptr);
    k_wconv<<<(LAYERS * 256 * 128 + 255) / 256, 256, 0, stream>>>(w_l, w_r, wT);

    k_inproj<<<(N_NODES * 128 + 255) / 256, 256, 0, stream>>>(x, kp_emb, w_in, b_in, h, hb);

    for (int l = 0; l < LAYERS; ++l) {
        k_gemm<<<(N_NODES + 31) / 32, 256, 0, stream>>>(hb, wT + (size_t)l * 256 * 128, xlb, xrb);
        k_gat<<<(N_NODES + 3) / 4, 256, 0, stream>>>(
            (const unsigned*)xlb, (const unsigned*)xrb, ptr, csrsrc,
            att + (size_t)l * 128, conv_b + (size_t)l * 128,
            bn_gamma + (size_t)l * 128, bn_beta + (size_t)l * 128,
            bn_mean + (size_t)l * 128, bn_var + (size_t)l * 128, h, hb);
    }

    k_pool_seg<<<N_GRAPHS, 256, 0, stream>>>(h, gptr, pool);
    k_mlp<<<N_GRAPHS, 256, 0, stream>>>(pool, gptr, w1, b1, w2, b2, w3, b3, out);
}

// Round 9
// 282.324 us; speedup vs baseline: 1.9621x; 1.0088x over previous
//
#include <hip/hip_runtime.h>
#include <hip/hip_bf16.h>

#define N_NODES 30000
#define N_EDGES 1000000
#define N_GRAPHS 256
#define HEADS 8
#define DHEAD 16
#define HIDDEN 128
#define LAYERS 3
#define KPN 17
#define KPE 16
#define NEG_SLOPE 0.2f
#define BN_EPS 1e-5f
#define ET (N_EDGES + N_NODES)
#define NBIN 235           /* ceil(30000/128) */
#define BINW 128           /* nodes per bin */
#define BINCAP 6144        /* mean load ~4266 */
#define CHUNK 4096

typedef __attribute__((ext_vector_type(8))) short bf16x8;
typedef __attribute__((ext_vector_type(4))) float f32x4;

__device__ __forceinline__ unsigned bf16_rne(float f) {
    unsigned u = __float_as_uint(f);
    return (u + 0x7fffu + ((u >> 16) & 1u)) >> 16;
}

// ---------------- CSR build: LDS-aggregated binned counting sort ----------------
__global__ __launch_bounds__(256) void k_bin(const int* __restrict__ ei,
                                             int* __restrict__ bcnt,
                                             unsigned* __restrict__ bdata) {
    __shared__ int lcnt[NBIN];
    __shared__ int lbase[NBIN];
    int base = blockIdx.x * CHUNK;
    int n = N_EDGES - base; if (n > CHUNK) n = CHUNK;
    for (int i = threadIdx.x; i < NBIN; i += 256) lcnt[i] = 0;
    __syncthreads();
    for (int t = threadIdx.x; t < n; t += 256) {
        int d = ei[N_EDGES + base + t];
        atomicAdd(&lcnt[d >> 7], 1);
    }
    __syncthreads();
    for (int i = threadIdx.x; i < NBIN; i += 256) {
        int c = lcnt[i];
        lbase[i] = c ? atomicAdd(&bcnt[i], c) : 0;
        lcnt[i] = 0;
    }
    __syncthreads();
    for (int t = threadIdx.x; t < n; t += 256) {
        int s = ei[base + t];
        int d = ei[N_EDGES + base + t];
        int b = d >> 7;
        int pos = lbase[b] + atomicAdd(&lcnt[b], 1);
        bdata[(size_t)b * BINCAP + pos] = (unsigned)s | ((unsigned)(d & 127) << 15);
    }
}

__global__ __launch_bounds__(256) void k_bscan(const int* __restrict__ bcnt,
                                               int* __restrict__ bbase,
                                               int* __restrict__ ptr) {
    __shared__ int v[256];
    int t = threadIdx.x;
    int c = 0;
    if (t < NBIN) {
        int nodes = N_NODES - t * BINW; if (nodes > BINW) nodes = BINW;
        c = bcnt[t] + nodes;
    }
    v[t] = c;
    __syncthreads();
    for (int off = 1; off < 256; off <<= 1) {
        int x = (t >= off) ? v[t - off] : 0;
        __syncthreads();
        v[t] += x;
        __syncthreads();
    }
    if (t < NBIN) bbase[t] = v[t] - c;
    if (t == 0) ptr[N_NODES] = ET;
}

__global__ __launch_bounds__(256) void k_place2(const int* __restrict__ bcnt,
                                                const unsigned* __restrict__ bdata,
                                                const int* __restrict__ bbase,
                                                int* __restrict__ ptr,
                                                unsigned short* __restrict__ csr_src) {
    __shared__ int hist[BINW];
    __shared__ int pre[BINW];
    __shared__ int nodestart[BINW];
    __shared__ int lofs[BINW];
    int b = blockIdx.x;
    int tid = threadIdx.x;
    int nNodes = N_NODES - b * BINW; if (nNodes > BINW) nNodes = BINW;
    int n = bcnt[b];
    if (tid < BINW) hist[tid] = (tid < nNodes) ? 1 : 0;   // self loop seed
    __syncthreads();
    for (int t = tid; t < n; t += 256)
        atomicAdd(&hist[(bdata[(size_t)b * BINCAP + t] >> 15) & 127], 1);
    __syncthreads();
    if (tid < BINW) pre[tid] = hist[tid];
    __syncthreads();
    for (int off = 1; off < BINW; off <<= 1) {
        int x = (tid >= off && tid < BINW) ? pre[tid - off] : 0;
        __syncthreads();
        if (tid < BINW) pre[tid] += x;
        __syncthreads();
    }
    if (tid < BINW) {
        int ns = bbase[b] + pre[tid] - hist[tid];
        nodestart[tid] = ns;
        if (tid < nNodes) {
            int node = b * BINW + tid;
            ptr[node] = ns;
            csr_src[ns] = (unsigned short)node;   // self loop
        }
        lofs[tid] = 1;
    }
    __syncthreads();
    for (int t = tid; t < n; t += 256) {
        unsigned e = bdata[(size_t)b * BINCAP + t];
        int dl = (e >> 15) & 127;
        int pos = nodestart[dl] + atomicAdd(&lofs[dl], 1);
        csr_src[pos] = (unsigned short)(e & 0x7fffu);
    }
}

// ---------------- graph segment boundaries ----------------
__global__ void k_gptr(const int* __restrict__ batch, int* __restrict__ gptr) {
    int g = blockIdx.x * 256 + threadIdx.x;
    if (g > N_GRAPHS) return;
    if (g == N_GRAPHS) { gptr[g] = N_NODES; return; }
    int lo = 0, hi = N_NODES;
    while (lo < hi) {
        int mid = (lo + hi) >> 1;
        if (batch[mid] < g) lo = mid + 1; else hi = mid;
    }
    gptr[g] = lo;
}

// ---------------- weight transpose+convert: wT[l][256 col][128 k] bf16 ----------------
__global__ void k_wconv(const float* __restrict__ w_l, const float* __restrict__ w_r,
                        unsigned short* __restrict__ wT) {
    int t = blockIdx.x * 256 + threadIdx.x;
    if (t >= LAYERS * 256 * 128) return;
    int l = t / (256 * 128);
    int rem = t - l * 256 * 128;
    int c = rem >> 7;
    int k = rem & 127;
    float v = (c < 128) ? w_l[(size_t)l * 16384 + k * 128 + c]
                        : w_r[(size_t)l * 16384 + k * 128 + (c - 128)];
    wT[t] = (unsigned short)bf16_rne(v);
}

// ---------------- input projection: h (f32) + hb (bf16) ----------------
__global__ void k_inproj(const float* __restrict__ x, const float* __restrict__ kp_emb,
                         const float* __restrict__ w_in, const float* __restrict__ b_in,
                         float* __restrict__ h, unsigned short* __restrict__ hb) {
    int t = blockIdx.x * 256 + threadIdx.x;
    if (t >= N_NODES * HIDDEN) return;
    int c = t & 127, i = t >> 7;
    float acc = b_in[c];
    const float* xi = x + i * 3;
    acc += xi[0] * w_in[0 * 128 + c];
    acc += xi[1] * w_in[1 * 128 + c];
    acc += xi[2] * w_in[2 * 128 + c];
    const float* kp = kp_emb + (i % KPN) * KPE;
#pragma unroll
    for (int k = 0; k < KPE; ++k) acc += kp[k] * w_in[(3 + k) * 128 + c];
    h[t] = acc;
    hb[t] = (unsigned short)bf16_rne(acc);
}

// ---------------- MFMA dual GEMM: [xl|xr](bf16) = hb(bf16) @ wT^T ----------------
__global__ __launch_bounds__(256) void k_gemm(const unsigned short* __restrict__ hb,
                                              const unsigned short* __restrict__ wT,
                                              unsigned short* __restrict__ xlb,
                                              unsigned short* __restrict__ xrb) {
    int wave = threadIdx.x >> 6;
    int lane = threadIdx.x & 63;
    int brow = blockIdx.x * 32;
    int lr = lane & 15;
    int lk = lane >> 4;
    int ar0 = brow + lr;
    int ar1 = brow + 16 + lr;
    int ar0c = ar0 < N_NODES ? ar0 : N_NODES - 1;
    int ar1c = ar1 < N_NODES ? ar1 : N_NODES - 1;
    int c0 = wave * 64 + lr;

    const unsigned short* ha0 = hb + (size_t)ar0c * 128 + lk * 8;
    const unsigned short* ha1 = hb + (size_t)ar1c * 128 + lk * 8;
    const unsigned short* wb  = wT + (size_t)c0 * 128 + lk * 8;

    f32x4 acc[2][4];
#pragma unroll
    for (int m = 0; m < 2; ++m)
#pragma unroll
        for (int n = 0; n < 4; ++n) acc[m][n] = (f32x4){0.f, 0.f, 0.f, 0.f};

#pragma unroll
    for (int ks = 0; ks < 4; ++ks) {
        bf16x8 a0 = *(const bf16x8*)(ha0 + ks * 32);
        bf16x8 a1 = *(const bf16x8*)(ha1 + ks * 32);
#pragma unroll
        for (int nt = 0; nt < 4; ++nt) {
            bf16x8 b = *(const bf16x8*)(wb + nt * 16 * 128 + ks * 32);
            acc[0][nt] = __builtin_amdgcn_mfma_f32_16x16x32_bf16(a0, b, acc[0][nt], 0, 0, 0);
            acc[1][nt] = __builtin_amdgcn_mfma_f32_16x16x32_bf16(a1, b, acc[1][nt], 0, 0, 0);
        }
    }

    int drow0 = brow + lk * 4;
#pragma unroll
    for (int mt = 0; mt < 2; ++mt) {
#pragma unroll
        for (int nt = 0; nt < 4; ++nt) {
            int col = c0 + nt * 16;
#pragma unroll
            for (int j = 0; j < 4; ++j) {
                int grow = drow0 + mt * 16 + j;
                if (grow >= N_NODES) continue;
                unsigned short bv = (unsigned short)bf16_rne(acc[mt][nt][j]);
                if (col < 128) xlb[(size_t)grow * 128 + col] = bv;
                else           xrb[(size_t)grow * 128 + (col - 128)] = bv;
            }
        }
    }
}

// ---------------- GATv2 per-node kernel ----------------
// 1 wave per node; 4 edges/iter (16 lanes each, 8 dims/lane, dwordx4 loads);
// no-max softmax; depth-2 quad pipeline (8 edges in flight)
__global__ __launch_bounds__(256) void k_gat(const uint4* __restrict__ xlb4,
                                             const uint4* __restrict__ xrb4,
                                             const int* __restrict__ ptr,
                                             const unsigned short* __restrict__ csr_src,
                                             const float* __restrict__ att_l,
                                             const float* __restrict__ bias_l,
                                             const float* __restrict__ gamma_l,
                                             const float* __restrict__ beta_l,
                                             const float* __restrict__ mean_l,
                                             const float* __restrict__ var_l,
                                             float* __restrict__ h,
                                             unsigned short* __restrict__ hb) {
    int wid = (blockIdx.x * 256 + threadIdx.x) >> 6;
    int lane = threadIdx.x & 63;
    if (wid >= N_NODES) return;
    int i = wid;
    int e4 = lane >> 4;      // edge slot within quad
    int l16 = lane & 15;
    int d0 = 8 * l16;

    uint4 xw = xrb4[(size_t)i * 16 + l16];
    float xr0 = __uint_as_float(xw.x << 16), xr1 = __uint_as_float(xw.x & 0xffff0000u);
    float xr2 = __uint_as_float(xw.y << 16), xr3 = __uint_as_float(xw.y & 0xffff0000u);
    float xr4 = __uint_as_float(xw.z << 16), xr5 = __uint_as_float(xw.z & 0xffff0000u);
    float xr6 = __uint_as_float(xw.w << 16), xr7 = __uint_as_float(xw.w & 0xffff0000u);
    const float L2E = 1.44269504089f;
    float4 avA = *(const float4*)(att_l + d0);
    float4 avB = *(const float4*)(att_l + d0 + 4);
    avA.x *= L2E; avA.y *= L2E; avA.z *= L2E; avA.w *= L2E;
    avB.x *= L2E; avB.y *= L2E; avB.z *= L2E; avB.w *= L2E;
    int e0 = ptr[i], e1 = ptr[i + 1];

    float denom = 0.f;
    float a0 = 0.f, a1 = 0.f, a2 = 0.f, a3 = 0.f, a4 = 0.f, a5 = 0.f, a6 = 0.f, a7 = 0.f;

#define LDQ(KQ, WREG, VREG) { \
    int eo = 4 * (KQ) + e4; \
    int sr = __shfl(sv, eo); \
    VREG = eo < cnt; \
    int rw = VREG ? sr : 0; \
    WREG = xlb4[(size_t)rw * 16 + l16]; \
}
#define PROCQ(WREG, VREG) { \
    float v0 = __uint_as_float(WREG.x << 16), v1 = __uint_as_float(WREG.x & 0xffff0000u); \
    float v2 = __uint_as_float(WREG.y << 16), v3 = __uint_as_float(WREG.y & 0xffff0000u); \
    float v4 = __uint_as_float(WREG.z << 16), v5 = __uint_as_float(WREG.z & 0xffff0000u); \
    float v6 = __uint_as_float(WREG.w << 16), v7 = __uint_as_float(WREG.w & 0xffff0000u); \
    float z0 = v0 + xr0, z1 = v1 + xr1, z2 = v2 + xr2, z3 = v3 + xr3; \
    float z4 = v4 + xr4, z5 = v5 + xr5, z6 = v6 + xr6, z7 = v7 + xr7; \
    z0 = fmaxf(z0, NEG_SLOPE * z0); z1 = fmaxf(z1, NEG_SLOPE * z1); \
    z2 = fmaxf(z2, NEG_SLOPE * z2); z3 = fmaxf(z3, NEG_SLOPE * z3); \
    z4 = fmaxf(z4, NEG_SLOPE * z4); z5 = fmaxf(z5, NEG_SLOPE * z5); \
    z6 = fmaxf(z6, NEG_SLOPE * z6); z7 = fmaxf(z7, NEG_SLOPE * z7); \
    float p = z0 * avA.x + z1 * avA.y + z2 * avA.z + z3 * avA.w \
            + z4 * avB.x + z5 * avB.y + z6 * avB.z + z7 * avB.w; \
    p += __shfl_xor(p, 1); \
    float ex = VREG ? exp2f(p) : 0.f; \
    denom += ex; \
    a0 += ex * v0; a1 += ex * v1; a2 += ex * v2; a3 += ex * v3; \
    a4 += ex * v4; a5 += ex * v5; a6 += ex * v6; a7 += ex * v7; \
}

    for (int base = e0; base < e1; base += 64) {
        int idx = base + lane;
        int sv = (idx < e1) ? (int)csr_src[idx] : 0;
        int cnt = e1 - base; if (cnt > 64) cnt = 64;
        int nq = (cnt + 3) >> 2;

        uint4 w0, w1; bool b0 = false, b1 = false;
        LDQ(0, w0, b0);
        if (1 < nq) LDQ(1, w1, b1);
        int k = 0;
        for (; k + 2 < nq; k += 2) {
            uint4 n0, n1; bool c0v, c1v;
            LDQ(k + 2, n0, c0v);
            LDQ(k + 3, n1, c1v);
            PROCQ(w0, b0); PROCQ(w1, b1);
            w0 = n0; b0 = c0v; w1 = n1; b1 = c1v;
        }
        PROCQ(w0, b0);
        if (k + 1 < nq) PROCQ(w1, b1);
    }
#undef LDQ
#undef PROCQ

    // combine the 4 edge groups (same dims, different edges)
    denom += __shfl_xor(denom, 16); denom += __shfl_xor(denom, 32);
    a0 += __shfl_xor(a0, 16); a0 += __shfl_xor(a0, 32);
    a1 += __shfl_xor(a1, 16); a1 += __shfl_xor(a1, 32);
    a2 += __shfl_xor(a2, 16); a2 += __shfl_xor(a2, 32);
    a3 += __shfl_xor(a3, 16); a3 += __shfl_xor(a3, 32);
    a4 += __shfl_xor(a4, 16); a4 += __shfl_xor(a4, 32);
    a5 += __shfl_xor(a5, 16); a5 += __shfl_xor(a5, 32);
    a6 += __shfl_xor(a6, 16); a6 += __shfl_xor(a6, 32);
    a7 += __shfl_xor(a7, 16); a7 += __shfl_xor(a7, 32);

    if (e4 == 0) {
        float inv = 1.f / denom;
        float4 biaA = *(const float4*)(bias_l + d0),  biaB = *(const float4*)(bias_l + d0 + 4);
        float4 gamA = *(const float4*)(gamma_l + d0), gamB = *(const float4*)(gamma_l + d0 + 4);
        float4 betA = *(const float4*)(beta_l + d0),  betB = *(const float4*)(beta_l + d0 + 4);
        float4 meaA = *(const float4*)(mean_l + d0),  meaB = *(const float4*)(mean_l + d0 + 4);
        float4 varA = *(const float4*)(var_l + d0),   varB = *(const float4*)(var_l + d0 + 4);
        float o0 = fmaxf(a0 * inv + biaA.x, 0.f);
        float o1 = fmaxf(a1 * inv + biaA.y, 0.f);
        float o2 = fmaxf(a2 * inv + biaA.z, 0.f);
        float o3 = fmaxf(a3 * inv + biaA.w, 0.f);
        float o4 = fmaxf(a4 * inv + biaB.x, 0.f);
        float o5 = fmaxf(a5 * inv + biaB.y, 0.f);
        float o6 = fmaxf(a6 * inv + biaB.z, 0.f);
        float o7 = fmaxf(a7 * inv + biaB.w, 0.f);
        o0 = (o0 - meaA.x) * (gamA.x * rsqrtf(varA.x + BN_EPS)) + betA.x;
        o1 = (o1 - meaA.y) * (gamA.y * rsqrtf(varA.y + BN_EPS)) + betA.y;
        o2 = (o2 - meaA.z) * (gamA.z * rsqrtf(varA.z + BN_EPS)) + betA.z;
        o3 = (o3 - meaA.w) * (gamA.w * rsqrtf(varA.w + BN_EPS)) + betA.w;
        o4 = (o4 - meaB.x) * (gamB.x * rsqrtf(varB.x + BN_EPS)) + betB.x;
        o5 = (o5 - meaB.y) * (gamB.y * rsqrtf(varB.y + BN_EPS)) + betB.y;
        o6 = (o6 - meaB.z) * (gamB.z * rsqrtf(varB.z + BN_EPS)) + betB.z;
        o7 = (o7 - meaB.w) * (gamB.w * rsqrtf(varB.w + BN_EPS)) + betB.w;
        float4 hvA = *(const float4*)(h + (size_t)i * 128 + d0);
        float4 hvB = *(const float4*)(h + (size_t)i * 128 + d0 + 4);
        hvA.x += o0; hvA.y += o1; hvA.z += o2; hvA.w += o3;
        hvB.x += o4; hvB.y += o5; hvB.z += o6; hvB.w += o7;
        *(float4*)(h + (size_t)i * 128 + d0) = hvA;
        *(float4*)(h + (size_t)i * 128 + d0 + 4) = hvB;
        uint4 pk;
        pk.x = bf16_rne(hvA.x) | (bf16_rne(hvA.y) << 16);
        pk.y = bf16_rne(hvA.z) | (bf16_rne(hvA.w) << 16);
        pk.z = bf16_rne(hvB.x) | (bf16_rne(hvB.y) << 16);
        pk.w = bf16_rne(hvB.z) | (bf16_rne(hvB.w) << 16);
        *(uint4*)(hb + (size_t)i * 128 + d0) = pk;
    }
}

// ---------------- fused pooling + classifier MLP (1 block per graph) ----------------
__global__ __launch_bounds__(256) void k_poolmlp(const float* __restrict__ h,
                                                 const int* __restrict__ gptr,
                                                 const float* __restrict__ w1, const float* __restrict__ b1,
                                                 const float* __restrict__ w2, const float* __restrict__ b2,
                                                 const float* __restrict__ w3, const float* __restrict__ b3,
                                                 float* __restrict__ out) {
    __shared__ float red[256];
    __shared__ float g[128], t1[256], t2[128];
    int b = blockIdx.x, t = threadIdx.x;
    int c = t & 127, half = t >> 7;
    int lo = gptr[b], hi = gptr[b + 1];
    float s = 0.f;
    for (int i = lo + half; i < hi; i += 2) s += h[(size_t)i * 128 + c];
    red[t] = s;
    __syncthreads();
    if (half == 0) {
        float cntf = fmaxf((float)(hi - lo), 1.0f);
        g[c] = (red[c] + red[c + 128]) / cntf;
    }
    __syncthreads();
    {
        float acc = b1[t];
        for (int k = 0; k < 128; ++k) acc += g[k] * w1[k * 256 + t];
        t1[t] = acc > 0.f ? acc : expm1f(acc);
    }
    __syncthreads();
    if (t < 128) {
        float acc = b2[t];
        for (int k = 0; k < 256; ++k) acc += t1[k] * w2[k * 128 + t];
        t2[t] = acc > 0.f ? acc : expm1f(acc);
    }
    __syncthreads();
    if (t < 2) {
        float acc = b3[t];
        for (int k = 0; k < 128; ++k) acc += t2[k] * w3[k * 2 + t];
        out[b * 2 + t] = acc;
    }
}

// ---------------- launch ----------------
extern "C" void kernel_launch(void* const* d_in, const int* in_sizes, int n_in,
                              void* d_out, int out_size, void* d_ws, size_t ws_size,
                              hipStream_t stream) {
    const float* x        = (const float*)d_in[0];
    const int*   ei       = (const int*)d_in[1];
    const int*   batch    = (const int*)d_in[2];
    const float* kp_emb   = (const float*)d_in[3];
    const float* w_in     = (const float*)d_in[4];
    const float* b_in     = (const float*)d_in[5];
    const float* w_l      = (const float*)d_in[6];
    const float* w_r      = (const float*)d_in[7];
    const float* att      = (const float*)d_in[8];
    const float* conv_b   = (const float*)d_in[9];
    const float* bn_gamma = (const float*)d_in[10];
    const float* bn_beta  = (const float*)d_in[11];
    const float* bn_mean  = (const float*)d_in[12];
    const float* bn_var   = (const float*)d_in[13];
    const float* w1 = (const float*)d_in[14];
    const float* b1 = (const float*)d_in[15];
    const float* w2 = (const float*)d_in[16];
    const float* b2 = (const float*)d_in[17];
    const float* w3 = (const float*)d_in[18];
    const float* b3 = (const float*)d_in[19];
    float* out = (float*)d_out;

    char* ws = (char*)d_ws;
    const size_t OFF_H    = 0;                                    // f32 h [30000][128]
    const size_t OFF_HB   = OFF_H    + 15360000;                  // bf16 h
    const size_t OFF_XL   = OFF_HB   + 7680000;                   // bf16 xl
    const size_t OFF_XR   = OFF_XL   + 7680000;                   // bf16 xr (bdata alias)
    const size_t OFF_WT   = OFF_XR   + 7680000;                   // bf16 wT [3][256][128]
    const size_t OFF_PTR  = OFF_WT   + 196608;
    const size_t OFF_BCNT = OFF_PTR  + 120320;
    const size_t OFF_BBAS = OFF_BCNT + 1024;
    const size_t OFF_SRC  = OFF_BBAS + 1024;                      // ushort csr [ET]
    const size_t OFF_GPTR = OFF_SRC  + 2060032;

    float*          h      = (float*)(ws + OFF_H);
    unsigned short* hb     = (unsigned short*)(ws + OFF_HB);
    unsigned short* xlb    = (unsigned short*)(ws + OFF_XL);
    unsigned short* xrb    = (unsigned short*)(ws + OFF_XR);
    unsigned*       bdata  = (unsigned*)(ws + OFF_XR);            // alias, pre-GEMM only
    unsigned short* wT     = (unsigned short*)(ws + OFF_WT);
    int*            ptr    = (int*)(ws + OFF_PTR);
    int*            bcnt   = (int*)(ws + OFF_BCNT);
    int*            bbase  = (int*)(ws + OFF_BBAS);
    unsigned short* csrsrc = (unsigned short*)(ws + OFF_SRC);
    int*            gptr   = (int*)(ws + OFF_GPTR);

    hipMemsetAsync(bcnt, 0, NBIN * 4, stream);
    k_bin<<<(N_EDGES + CHUNK - 1) / CHUNK, 256, 0, stream>>>(ei, bcnt, bdata);
    k_bscan<<<1, 256, 0, stream>>>(bcnt, bbase, ptr);
    k_place2<<<NBIN, 256, 0, stream>>>(bcnt, bdata, bbase, ptr, csrsrc);
    k_gptr<<<2, 256, 0, stream>>>(batch, gptr);
    k_wconv<<<(LAYERS * 256 * 128 + 255) / 256, 256, 0, stream>>>(w_l, w_r, wT);

    k_inproj<<<(N_NODES * 128 + 255) / 256, 256, 0, stream>>>(x, kp_emb, w_in, b_in, h, hb);

    for (int l = 0; l < LAYERS; ++l) {
        k_gemm<<<(N_NODES + 31) / 32, 256, 0, stream>>>(hb, wT + (size_t)l * 256 * 128, xlb, xrb);
        k_gat<<<(N_NODES + 3) / 4, 256, 0, stream>>>(
            (const uint4*)xlb, (const uint4*)xrb, ptr, csrsrc,
            att + (size_t)l * 128, conv_b + (size_t)l * 128,
            bn_gamma + (size_t)l * 128, bn_beta + (size_t)l * 128,
            bn_mean + (size_t)l * 128, bn_var + (size_t)l * 128, h, hb);
    }

    k_poolmlp<<<N_GRAPHS, 256, 0, stream>>>(h, gptr, w1, b1, w2, b2, w3, b3, out);
}

// Round 10
// 280.340 us; speedup vs baseline: 1.9760x; 1.0071x over previous
//
#include <hip/hip_runtime.h>
#include <hip/hip_bf16.h>

#define N_NODES 30000
#define N_EDGES 1000000
#define N_GRAPHS 256
#define HEADS 8
#define DHEAD 16
#define HIDDEN 128
#define LAYERS 3
#define KPN 17
#define KPE 16
#define NEG_SLOPE 0.2f
#define BN_EPS 1e-5f
#define ET (N_EDGES + N_NODES)
#define NBIN 235           /* ceil(30000/128) */
#define BINW 128           /* nodes per bin */
#define BINCAP 6144        /* mean load ~4266 */
#define CHUNK 4096

typedef __attribute__((ext_vector_type(8))) short bf16x8;
typedef __attribute__((ext_vector_type(4))) float f32x4;

__device__ __forceinline__ unsigned bf16_rne(float f) {
    unsigned u = __float_as_uint(f);
    return (u + 0x7fffu + ((u >> 16) & 1u)) >> 16;
}

// ---------------- CSR build: LDS-aggregated binned counting sort ----------------
__global__ __launch_bounds__(256) void k_bin(const int* __restrict__ ei,
                                             int* __restrict__ bcnt,
                                             unsigned* __restrict__ bdata) {
    __shared__ int lcnt[NBIN];
    __shared__ int lbase[NBIN];
    int base = blockIdx.x * CHUNK;
    int n = N_EDGES - base; if (n > CHUNK) n = CHUNK;
    for (int i = threadIdx.x; i < NBIN; i += 256) lcnt[i] = 0;
    __syncthreads();
    for (int t = threadIdx.x; t < n; t += 256) {
        int d = ei[N_EDGES + base + t];
        atomicAdd(&lcnt[d >> 7], 1);
    }
    __syncthreads();
    for (int i = threadIdx.x; i < NBIN; i += 256) {
        int c = lcnt[i];
        lbase[i] = c ? atomicAdd(&bcnt[i], c) : 0;
        lcnt[i] = 0;
    }
    __syncthreads();
    for (int t = threadIdx.x; t < n; t += 256) {
        int s = ei[base + t];
        int d = ei[N_EDGES + base + t];
        int b = d >> 7;
        int pos = lbase[b] + atomicAdd(&lcnt[b], 1);
        bdata[(size_t)b * BINCAP + pos] = (unsigned)s | ((unsigned)(d & 127) << 15);
    }
}

// fused aux: block 0 = gptr + bin-scan; blocks 1..384 = weight convert
__global__ __launch_bounds__(256) void k_aux(const int* __restrict__ bcnt,
                                             const int* __restrict__ batch,
                                             const float* __restrict__ w_l,
                                             const float* __restrict__ w_r,
                                             int* __restrict__ bbase,
                                             int* __restrict__ ptr,
                                             int* __restrict__ gptr,
                                             unsigned short* __restrict__ wT) {
    int t = threadIdx.x;
    if (blockIdx.x == 0) {
        // gptr (batch is sorted)
        for (int g = t; g <= N_GRAPHS; g += 256) {
            if (g == N_GRAPHS) { gptr[g] = N_NODES; }
            else {
                int lo = 0, hi = N_NODES;
                while (lo < hi) {
                    int mid = (lo + hi) >> 1;
                    if (batch[mid] < g) lo = mid + 1; else hi = mid;
                }
                gptr[g] = lo;
            }
        }
        // bin scan
        __shared__ int v[256];
        int c = 0;
        if (t < NBIN) {
            int nodes = N_NODES - t * BINW; if (nodes > BINW) nodes = BINW;
            c = bcnt[t] + nodes;
        }
        v[t] = c;
        __syncthreads();
        for (int off = 1; off < 256; off <<= 1) {
            int x = (t >= off) ? v[t - off] : 0;
            __syncthreads();
            v[t] += x;
            __syncthreads();
        }
        if (t < NBIN) bbase[t] = v[t] - c;
        if (t == 0) ptr[N_NODES] = ET;
    } else {
        int idx = (blockIdx.x - 1) * 256 + t;
        if (idx < LAYERS * 256 * 128) {
            int l = idx / (256 * 128);
            int rem = idx - l * 256 * 128;
            int c = rem >> 7;
            int k = rem & 127;
            float v = (c < 128) ? w_l[(size_t)l * 16384 + k * 128 + c]
                                : w_r[(size_t)l * 16384 + k * 128 + (c - 128)];
            wT[idx] = (unsigned short)bf16_rne(v);
        }
    }
}

__global__ __launch_bounds__(256) void k_place2(const int* __restrict__ bcnt,
                                                const unsigned* __restrict__ bdata,
                                                const int* __restrict__ bbase,
                                                int* __restrict__ ptr,
                                                unsigned short* __restrict__ csr_src) {
    __shared__ int hist[BINW];
    __shared__ int pre[BINW];
    __shared__ int nodestart[BINW];
    __shared__ int lofs[BINW];
    int b = blockIdx.x;
    int tid = threadIdx.x;
    int nNodes = N_NODES - b * BINW; if (nNodes > BINW) nNodes = BINW;
    int n = bcnt[b];
    if (tid < BINW) hist[tid] = (tid < nNodes) ? 1 : 0;   // self loop seed
    __syncthreads();
    for (int t = tid; t < n; t += 256)
        atomicAdd(&hist[(bdata[(size_t)b * BINCAP + t] >> 15) & 127], 1);
    __syncthreads();
    if (tid < BINW) pre[tid] = hist[tid];
    __syncthreads();
    for (int off = 1; off < BINW; off <<= 1) {
        int x = (tid >= off && tid < BINW) ? pre[tid - off] : 0;
        __syncthreads();
        if (tid < BINW) pre[tid] += x;
        __syncthreads();
    }
    if (tid < BINW) {
        int ns = bbase[b] + pre[tid] - hist[tid];
        nodestart[tid] = ns;
        if (tid < nNodes) {
            int node = b * BINW + tid;
            ptr[node] = ns;
            csr_src[ns] = (unsigned short)node;   // self loop
        }
        lofs[tid] = 1;
    }
    __syncthreads();
    for (int t = tid; t < n; t += 256) {
        unsigned e = bdata[(size_t)b * BINCAP + t];
        int dl = (e >> 15) & 127;
        int pos = nodestart[dl] + atomicAdd(&lofs[dl], 1);
        csr_src[pos] = (unsigned short)(e & 0x7fffu);
    }
}

// ---------------- input projection: h (f32) + hb (bf16) ----------------
__global__ void k_inproj(const float* __restrict__ x, const float* __restrict__ kp_emb,
                         const float* __restrict__ w_in, const float* __restrict__ b_in,
                         float* __restrict__ h, unsigned short* __restrict__ hb) {
    int t = blockIdx.x * 256 + threadIdx.x;
    if (t >= N_NODES * HIDDEN) return;
    int c = t & 127, i = t >> 7;
    float acc = b_in[c];
    const float* xi = x + i * 3;
    acc += xi[0] * w_in[0 * 128 + c];
    acc += xi[1] * w_in[1 * 128 + c];
    acc += xi[2] * w_in[2 * 128 + c];
    const float* kp = kp_emb + (i % KPN) * KPE;
#pragma unroll
    for (int k = 0; k < KPE; ++k) acc += kp[k] * w_in[(3 + k) * 128 + c];
    h[t] = acc;
    hb[t] = (unsigned short)bf16_rne(acc);
}

// ---------------- MFMA dual GEMM: [xl|xr](bf16) = hb(bf16) @ wT^T ----------------
__global__ __launch_bounds__(256) void k_gemm(const unsigned short* __restrict__ hb,
                                              const unsigned short* __restrict__ wT,
                                              unsigned short* __restrict__ xlb,
                                              unsigned short* __restrict__ xrb) {
    int wave = threadIdx.x >> 6;
    int lane = threadIdx.x & 63;
    int brow = blockIdx.x * 32;
    int lr = lane & 15;
    int lk = lane >> 4;
    int ar0 = brow + lr;
    int ar1 = brow + 16 + lr;
    int ar0c = ar0 < N_NODES ? ar0 : N_NODES - 1;
    int ar1c = ar1 < N_NODES ? ar1 : N_NODES - 1;
    int c0 = wave * 64 + lr;

    const unsigned short* ha0 = hb + (size_t)ar0c * 128 + lk * 8;
    const unsigned short* ha1 = hb + (size_t)ar1c * 128 + lk * 8;
    const unsigned short* wb  = wT + (size_t)c0 * 128 + lk * 8;

    f32x4 acc[2][4];
#pragma unroll
    for (int m = 0; m < 2; ++m)
#pragma unroll
        for (int n = 0; n < 4; ++n) acc[m][n] = (f32x4){0.f, 0.f, 0.f, 0.f};

#pragma unroll
    for (int ks = 0; ks < 4; ++ks) {
        bf16x8 a0 = *(const bf16x8*)(ha0 + ks * 32);
        bf16x8 a1 = *(const bf16x8*)(ha1 + ks * 32);
#pragma unroll
        for (int nt = 0; nt < 4; ++nt) {
            bf16x8 b = *(const bf16x8*)(wb + nt * 16 * 128 + ks * 32);
            acc[0][nt] = __builtin_amdgcn_mfma_f32_16x16x32_bf16(a0, b, acc[0][nt], 0, 0, 0);
            acc[1][nt] = __builtin_amdgcn_mfma_f32_16x16x32_bf16(a1, b, acc[1][nt], 0, 0, 0);
        }
    }

    int drow0 = brow + lk * 4;
#pragma unroll
    for (int mt = 0; mt < 2; ++mt) {
#pragma unroll
        for (int nt = 0; nt < 4; ++nt) {
            int col = c0 + nt * 16;
#pragma unroll
            for (int j = 0; j < 4; ++j) {
                int grow = drow0 + mt * 16 + j;
                if (grow >= N_NODES) continue;
                unsigned short bv = (unsigned short)bf16_rne(acc[mt][nt][j]);
                if (col < 128) xlb[(size_t)grow * 128 + col] = bv;
                else           xrb[(size_t)grow * 128 + (col - 128)] = bv;
            }
        }
    }
}

// ---------------- GATv2 per-node kernel ----------------
// 1 wave per node; 4 edges/iter (16 lanes each, 8 dims/lane, dwordx4 loads);
// leaky(z) = 0.6z + 0.4|z| (exact for slope 0.2) -> packed-f32-friendly fma streams
__global__ __launch_bounds__(256) void k_gat(const uint4* __restrict__ xlb4,
                                             const uint4* __restrict__ xrb4,
                                             const int* __restrict__ ptr,
                                             const unsigned short* __restrict__ csr_src,
                                             const float* __restrict__ att_l,
                                             const float* __restrict__ bias_l,
                                             const float* __restrict__ gamma_l,
                                             const float* __restrict__ beta_l,
                                             const float* __restrict__ mean_l,
                                             const float* __restrict__ var_l,
                                             float* __restrict__ h,
                                             unsigned short* __restrict__ hb) {
    int wid = (blockIdx.x * 256 + threadIdx.x) >> 6;
    int lane = threadIdx.x & 63;
    if (wid >= N_NODES) return;
    int i = wid;
    int e4 = lane >> 4;      // edge slot within quad
    int l16 = lane & 15;
    int d0 = 8 * l16;

    uint4 xw = xrb4[(size_t)i * 16 + l16];
    float2 xra = make_float2(__uint_as_float(xw.x << 16), __uint_as_float(xw.x & 0xffff0000u));
    float2 xrb_ = make_float2(__uint_as_float(xw.y << 16), __uint_as_float(xw.y & 0xffff0000u));
    float2 xrc = make_float2(__uint_as_float(xw.z << 16), __uint_as_float(xw.z & 0xffff0000u));
    float2 xrd = make_float2(__uint_as_float(xw.w << 16), __uint_as_float(xw.w & 0xffff0000u));
    const float L2E = 1.44269504089f;
    float4 avA = *(const float4*)(att_l + d0);
    float4 avB = *(const float4*)(att_l + d0 + 4);
    // a6 = 0.6*a*log2e (linear part), a4 = 0.4*a*log2e (abs part)
    float2 a6a = make_float2(avA.x * (0.6f * L2E), avA.y * (0.6f * L2E));
    float2 a6b = make_float2(avA.z * (0.6f * L2E), avA.w * (0.6f * L2E));
    float2 a6c = make_float2(avB.x * (0.6f * L2E), avB.y * (0.6f * L2E));
    float2 a6d = make_float2(avB.z * (0.6f * L2E), avB.w * (0.6f * L2E));
    float2 a4a = make_float2(avA.x * (0.4f * L2E), avA.y * (0.4f * L2E));
    float2 a4b = make_float2(avA.z * (0.4f * L2E), avA.w * (0.4f * L2E));
    float2 a4c = make_float2(avB.x * (0.4f * L2E), avB.y * (0.4f * L2E));
    float2 a4d = make_float2(avB.z * (0.4f * L2E), avB.w * (0.4f * L2E));
    int e0 = ptr[i], e1 = ptr[i + 1];

    float denom = 0.f;
    float2 acA = make_float2(0.f, 0.f), acB = make_float2(0.f, 0.f);
    float2 acC = make_float2(0.f, 0.f), acD = make_float2(0.f, 0.f);

#define LDQ(KQ, WREG, VREG) { \
    int eo = 4 * (KQ) + e4; \
    int sr = __shfl(sv, eo); \
    VREG = eo < cnt; \
    int rw = VREG ? sr : 0; \
    WREG = xlb4[(size_t)rw * 16 + l16]; \
}
#define PROCQ(WREG, VREG) { \
    float2 va = make_float2(__uint_as_float(WREG.x << 16), __uint_as_float(WREG.x & 0xffff0000u)); \
    float2 vb = make_float2(__uint_as_float(WREG.y << 16), __uint_as_float(WREG.y & 0xffff0000u)); \
    float2 vc = make_float2(__uint_as_float(WREG.z << 16), __uint_as_float(WREG.z & 0xffff0000u)); \
    float2 vd = make_float2(__uint_as_float(WREG.w << 16), __uint_as_float(WREG.w & 0xffff0000u)); \
    float2 za, zb, zc, zd; \
    za.x = va.x + xra.x;  za.y = va.y + xra.y; \
    zb.x = vb.x + xrb_.x; zb.y = vb.y + xrb_.y; \
    zc.x = vc.x + xrc.x;  zc.y = vc.y + xrc.y; \
    zd.x = vd.x + xrd.x;  zd.y = vd.y + xrd.y; \
    float2 p6, p4; \
    p6.x = za.x * a6a.x;  p6.y = za.y * a6a.y; \
    p6.x = fmaf(zb.x, a6b.x, p6.x); p6.y = fmaf(zb.y, a6b.y, p6.y); \
    p6.x = fmaf(zc.x, a6c.x, p6.x); p6.y = fmaf(zc.y, a6c.y, p6.y); \
    p6.x = fmaf(zd.x, a6d.x, p6.x); p6.y = fmaf(zd.y, a6d.y, p6.y); \
    p4.x = fabsf(za.x) * a4a.x;  p4.y = fabsf(za.y) * a4a.y; \
    p4.x = fmaf(fabsf(zb.x), a4b.x, p4.x); p4.y = fmaf(fabsf(zb.y), a4b.y, p4.y); \
    p4.x = fmaf(fabsf(zc.x), a4c.x, p4.x); p4.y = fmaf(fabsf(zc.y), a4c.y, p4.y); \
    p4.x = fmaf(fabsf(zd.x), a4d.x, p4.x); p4.y = fmaf(fabsf(zd.y), a4d.y, p4.y); \
    float p = (p6.x + p4.x) + (p6.y + p4.y); \
    p += __shfl_xor(p, 1); \
    float ex = VREG ? exp2f(p) : 0.f; \
    denom += ex; \
    acA.x = fmaf(ex, va.x, acA.x); acA.y = fmaf(ex, va.y, acA.y); \
    acB.x = fmaf(ex, vb.x, acB.x); acB.y = fmaf(ex, vb.y, acB.y); \
    acC.x = fmaf(ex, vc.x, acC.x); acC.y = fmaf(ex, vc.y, acC.y); \
    acD.x = fmaf(ex, vd.x, acD.x); acD.y = fmaf(ex, vd.y, acD.y); \
}

    for (int base = e0; base < e1; base += 64) {
        int idx = base + lane;
        int sv = (idx < e1) ? (int)csr_src[idx] : 0;
        int cnt = e1 - base; if (cnt > 64) cnt = 64;
        int nq = (cnt + 3) >> 2;

        uint4 w0, w1; bool b0 = false, b1 = false;
        LDQ(0, w0, b0);
        if (1 < nq) LDQ(1, w1, b1);
        int k = 0;
        for (; k + 2 < nq; k += 2) {
            uint4 n0, n1; bool c0v, c1v;
            LDQ(k + 2, n0, c0v);
            LDQ(k + 3, n1, c1v);
            PROCQ(w0, b0); PROCQ(w1, b1);
            w0 = n0; b0 = c0v; w1 = n1; b1 = c1v;
        }
        PROCQ(w0, b0);
        if (k + 1 < nq) PROCQ(w1, b1);
    }
#undef LDQ
#undef PROCQ

    // combine the 4 edge groups (same dims, different edges)
    denom += __shfl_xor(denom, 16); denom += __shfl_xor(denom, 32);
    acA.x += __shfl_xor(acA.x, 16); acA.x += __shfl_xor(acA.x, 32);
    acA.y += __shfl_xor(acA.y, 16); acA.y += __shfl_xor(acA.y, 32);
    acB.x += __shfl_xor(acB.x, 16); acB.x += __shfl_xor(acB.x, 32);
    acB.y += __shfl_xor(acB.y, 16); acB.y += __shfl_xor(acB.y, 32);
    acC.x += __shfl_xor(acC.x, 16); acC.x += __shfl_xor(acC.x, 32);
    acC.y += __shfl_xor(acC.y, 16); acC.y += __shfl_xor(acC.y, 32);
    acD.x += __shfl_xor(acD.x, 16); acD.x += __shfl_xor(acD.x, 32);
    acD.y += __shfl_xor(acD.y, 16); acD.y += __shfl_xor(acD.y, 32);

    if (e4 == 0) {
        float inv = 1.f / denom;
        float4 biaA = *(const float4*)(bias_l + d0),  biaB = *(const float4*)(bias_l + d0 + 4);
        float4 gamA = *(const float4*)(gamma_l + d0), gamB = *(const float4*)(gamma_l + d0 + 4);
        float4 betA = *(const float4*)(beta_l + d0),  betB = *(const float4*)(beta_l + d0 + 4);
        float4 meaA = *(const float4*)(mean_l + d0),  meaB = *(const float4*)(mean_l + d0 + 4);
        float4 varA = *(const float4*)(var_l + d0),   varB = *(const float4*)(var_l + d0 + 4);
        float o0 = fmaxf(acA.x * inv + biaA.x, 0.f);
        float o1 = fmaxf(acA.y * inv + biaA.y, 0.f);
        float o2 = fmaxf(acB.x * inv + biaA.z, 0.f);
        float o3 = fmaxf(acB.y * inv + biaA.w, 0.f);
        float o4 = fmaxf(acC.x * inv + biaB.x, 0.f);
        float o5 = fmaxf(acC.y * inv + biaB.y, 0.f);
        float o6 = fmaxf(acD.x * inv + biaB.z, 0.f);
        float o7 = fmaxf(acD.y * inv + biaB.w, 0.f);
        o0 = (o0 - meaA.x) * (gamA.x * rsqrtf(varA.x + BN_EPS)) + betA.x;
        o1 = (o1 - meaA.y) * (gamA.y * rsqrtf(varA.y + BN_EPS)) + betA.y;
        o2 = (o2 - meaA.z) * (gamA.z * rsqrtf(varA.z + BN_EPS)) + betA.z;
        o3 = (o3 - meaA.w) * (gamA.w * rsqrtf(varA.w + BN_EPS)) + betA.w;
        o4 = (o4 - meaB.x) * (gamB.x * rsqrtf(varB.x + BN_EPS)) + betB.x;
        o5 = (o5 - meaB.y) * (gamB.y * rsqrtf(varB.y + BN_EPS)) + betB.y;
        o6 = (o6 - meaB.z) * (gamB.z * rsqrtf(varB.z + BN_EPS)) + betB.z;
        o7 = (o7 - meaB.w) * (gamB.w * rsqrtf(varB.w + BN_EPS)) + betB.w;
        float4 hvA = *(const float4*)(h + (size_t)i * 128 + d0);
        float4 hvB = *(const float4*)(h + (size_t)i * 128 + d0 + 4);
        hvA.x += o0; hvA.y += o1; hvA.z += o2; hvA.w += o3;
        hvB.x += o4; hvB.y += o5; hvB.z += o6; hvB.w += o7;
        *(float4*)(h + (size_t)i * 128 + d0) = hvA;
        *(float4*)(h + (size_t)i * 128 + d0 + 4) = hvB;
        uint4 pk;
        pk.x = bf16_rne(hvA.x) | (bf16_rne(hvA.y) << 16);
        pk.y = bf16_rne(hvA.z) | (bf16_rne(hvA.w) << 16);
        pk.z = bf16_rne(hvB.x) | (bf16_rne(hvB.y) << 16);
        pk.w = bf16_rne(hvB.z) | (bf16_rne(hvB.w) << 16);
        *(uint4*)(hb + (size_t)i * 128 + d0) = pk;
    }
}

// ---------------- fused pooling + classifier MLP (1 block per graph) ----------------
__global__ __launch_bounds__(256) void k_poolmlp(const float* __restrict__ h,
                                                 const int* __restrict__ gptr,
                                                 const float* __restrict__ w1, const float* __restrict__ b1,
                                                 const float* __restrict__ w2, const float* __restrict__ b2,
                                                 const float* __restrict__ w3, const float* __restrict__ b3,
                                                 float* __restrict__ out) {
    __shared__ float red[256];
    __shared__ float g[128], t1[256], t2[128];
    int b = blockIdx.x, t = threadIdx.x;
    int c = t & 127, half = t >> 7;
    int lo = gptr[b], hi = gptr[b + 1];
    float s = 0.f;
    for (int i = lo + half; i < hi; i += 2) s += h[(size_t)i * 128 + c];
    red[t] = s;
    __syncthreads();
    if (half == 0) {
        float cntf = fmaxf((float)(hi - lo), 1.0f);
        g[c] = (red[c] + red[c + 128]) / cntf;
    }
    __syncthreads();
    {
        float acc = b1[t];
        for (int k = 0; k < 128; ++k) acc += g[k] * w1[k * 256 + t];
        t1[t] = acc > 0.f ? acc : expm1f(acc);
    }
    __syncthreads();
    if (t < 128) {
        float acc = b2[t];
        for (int k = 0; k < 256; ++k) acc += t1[k] * w2[k * 128 + t];
        t2[t] = acc > 0.f ? acc : expm1f(acc);
    }
    __syncthreads();
    if (t < 2) {
        float acc = b3[t];
        for (int k = 0; k < 128; ++k) acc += t2[k] * w3[k * 2 + t];
        out[b * 2 + t] = acc;
    }
}

// ---------------- launch ----------------
extern "C" void kernel_launch(void* const* d_in, const int* in_sizes, int n_in,
                              void* d_out, int out_size, void* d_ws, size_t ws_size,
                              hipStream_t stream) {
    const float* x        = (const float*)d_in[0];
    const int*   ei       = (const int*)d_in[1];
    const int*   batch    = (const int*)d_in[2];
    const float* kp_emb   = (const float*)d_in[3];
    const float* w_in     = (const float*)d_in[4];
    const float* b_in     = (const float*)d_in[5];
    const float* w_l      = (const float*)d_in[6];
    const float* w_r      = (const float*)d_in[7];
    const float* att      = (const float*)d_in[8];
    const float* conv_b   = (const float*)d_in[9];
    const float* bn_gamma = (const float*)d_in[10];
    const float* bn_beta  = (const float*)d_in[11];
    const float* bn_mean  = (const float*)d_in[12];
    const float* bn_var   = (const float*)d_in[13];
    const float* w1 = (const float*)d_in[14];
    const float* b1 = (const float*)d_in[15];
    const float* w2 = (const float*)d_in[16];
    const float* b2 = (const float*)d_in[17];
    const float* w3 = (const float*)d_in[18];
    const float* b3 = (const float*)d_in[19];
    float* out = (float*)d_out;

    char* ws = (char*)d_ws;
    const size_t OFF_H    = 0;                                    // f32 h [30000][128]
    const size_t OFF_HB   = OFF_H    + 15360000;                  // bf16 h
    const size_t OFF_XL   = OFF_HB   + 7680000;                   // bf16 xl
    const size_t OFF_XR   = OFF_XL   + 7680000;                   // bf16 xr (bdata alias)
    const size_t OFF_WT   = OFF_XR   + 7680000;                   // bf16 wT [3][256][128]
    const size_t OFF_PTR  = OFF_WT   + 196608;
    const size_t OFF_BCNT = OFF_PTR  + 120320;
    const size_t OFF_BBAS = OFF_BCNT + 1024;
    const size_t OFF_SRC  = OFF_BBAS + 1024;                      // ushort csr [ET]
    const size_t OFF_GPTR = OFF_SRC  + 2060032;

    float*          h      = (float*)(ws + OFF_H);
    unsigned short* hb     = (unsigned short*)(ws + OFF_HB);
    unsigned short* xlb    = (unsigned short*)(ws + OFF_XL);
    unsigned short* xrb    = (unsigned short*)(ws + OFF_XR);
    unsigned*       bdata  = (unsigned*)(ws + OFF_XR);            // alias, pre-GEMM only
    unsigned short* wT     = (unsigned short*)(ws + OFF_WT);
    int*            ptr    = (int*)(ws + OFF_PTR);
    int*            bcnt   = (int*)(ws + OFF_BCNT);
    int*            bbase  = (int*)(ws + OFF_BBAS);
    unsigned short* csrsrc = (unsigned short*)(ws + OFF_SRC);
    int*            gptr   = (int*)(ws + OFF_GPTR);

    hipMemsetAsync(bcnt, 0, NBIN * 4, stream);
    k_bin<<<(N_EDGES + CHUNK - 1) / CHUNK, 256, 0, stream>>>(ei, bcnt, bdata);
    k_aux<<<1 + (LAYERS * 256 * 128 + 255) / 256, 256, 0, stream>>>(bcnt, batch, w_l, w_r,
                                                                    bbase, ptr, gptr, wT);
    k_place2<<<NBIN, 256, 0, stream>>>(bcnt, bdata, bbase, ptr, csrsrc);

    k_inproj<<<(N_NODES * 128 + 255) / 256, 256, 0, stream>>>(x, kp_emb, w_in, b_in, h, hb);

    for (int l = 0; l < LAYERS; ++l) {
        k_gemm<<<(N_NODES + 31) / 32, 256, 0, stream>>>(hb, wT + (size_t)l * 256 * 128, xlb, xrb);
        k_gat<<<(N_NODES + 3) / 4, 256, 0, stream>>>(
            (const uint4*)xlb, (const uint4*)xrb, ptr, csrsrc,
            att + (size_t)l * 128, conv_b + (size_t)l * 128,
            bn_gamma + (size_t)l * 128, bn_beta + (size_t)l * 128,
            bn_mean + (size_t)l * 128, bn_var + (size_t)l * 128, h, hb);
    }

    k_poolmlp<<<N_GRAPHS, 256, 0, stream>>>(h, gptr, w1, b1, w2, b2, w3, b3, out);
}